// Round 1
// baseline (1681.790 us; speedup 1.0000x reference)
//
#include <hip/hip_runtime.h>
#include <cstddef>
#include <cstdint>

constexpr int kC = 192;    // channels
constexpr int kW = 512;    // sequence length (width)
constexpr int kHH = 48;    // H
// N sequences = B*H = 96

// ---------------- LayerNorm + transpose: x[b,c,h,w] -> out[n,w,c] normalized over c ----
__global__ void __launch_bounds__(256) ln_kernel(
    const float* __restrict__ x, const float* __restrict__ g,
    const float* __restrict__ b, float* __restrict__ out) {
  int n = blockIdx.y;
  int w0 = blockIdx.x * 64;
  int bb = n / kHH, h = n % kHH;
  __shared__ float tile[64][193];
  __shared__ float red[8][64];
  __shared__ float mean_s[64], rstd_s[64];
  int tid = threadIdx.x;
  int lane = tid & 63, wv = tid >> 6;
  for (int c = wv; c < kC; c += 4) {
    tile[lane][c] = x[(((size_t)bb * kC + c) * kHH + h) * kW + w0 + lane];
  }
  __syncthreads();
  {
    int w = tid & 63, part = tid >> 6;
    float s = 0.f, s2 = 0.f;
    const float* row = &tile[w][0];
    for (int c = part * 48; c < part * 48 + 48; ++c) {
      float v = row[c];
      s += v; s2 += v * v;
    }
    red[part][w] = s;
    red[part + 4][w] = s2;
  }
  __syncthreads();
  if (tid < 64) {
    float s = red[0][tid] + red[1][tid] + red[2][tid] + red[3][tid];
    float s2 = red[4][tid] + red[5][tid] + red[6][tid] + red[7][tid];
    float m = s * (1.f / 192.f);
    float var = s2 * (1.f / 192.f) - m * m;
    mean_s[tid] = m;
    rstd_s[tid] = rsqrtf(var + 1e-5f);
  }
  __syncthreads();
  for (int e = tid; e < 64 * kC; e += 256) {
    int w = e / kC, c = e % kC;
    out[((size_t)n * kW + w0 + w) * kC + c] =
        (tile[w][c] - mean_s[w]) * rstd_s[w] * g[c] + b[c];
  }
}

// ---------------- conv weight transpose: w[o,c,t] -> wt[(t*192+c)*Cout + o] ----------
__global__ void wprep_conv(const float* __restrict__ w, float* __restrict__ wt,
                           int total, int Cout) {
  int idx = blockIdx.x * 256 + threadIdx.x;
  if (idx >= total) return;
  int o = idx % Cout;
  int rest = idx / Cout;
  int c = rest % kC;
  int t = rest / kC;
  wt[idx] = w[((size_t)o * kC + c) * 3 + t];
}

// ---------------- conv1d(k=3, same) as GEMM: out[(n*2+h)*512+l][Eh] -------------------
// RAWIN=false: in = buffer [n][l][c].  RAWIN=true: in = raw tensor [b][c][h][w].
template <bool RAWIN>
__global__ void __launch_bounds__(256) conv_gemm(
    const float* __restrict__ in, const float* __restrict__ wt,
    const float* __restrict__ bias, float* __restrict__ out,
    int Cout, int Eh) {
  int l0 = blockIdx.x * 64;
  int o0 = blockIdx.y * 64;
  int n = blockIdx.z;
  int bb = n / kHH, h = n % kHH;
  __shared__ float As[64][17];  // [l-row][c-chunk]
  __shared__ float Bs[16][68];  // [c-chunk][o]
  int tid = threadIdx.x;
  int ty = tid >> 4, tx = tid & 15;
  float acc[4][4] = {};
  for (int t = 0; t < 3; ++t) {
    for (int c0 = 0; c0 < kC; c0 += 16) {
      if (!RAWIN) {
        int i = tid >> 2, q = tid & 3;
        int l = l0 + i + t - 1;
        float4 v = make_float4(0.f, 0.f, 0.f, 0.f);
        if (l >= 0 && l < kW)
          v = *reinterpret_cast<const float4*>(in + ((size_t)n * kW + l) * kC + c0 + q * 4);
        As[i][q * 4 + 0] = v.x;
        As[i][q * 4 + 1] = v.y;
        As[i][q * 4 + 2] = v.z;
        As[i][q * 4 + 3] = v.w;
      } else {
        int cc = tid >> 4, i0 = (tid & 15) * 4;
        const float* p = in + (((size_t)bb * kC + c0 + cc) * kHH + h) * kW;
#pragma unroll
        for (int m = 0; m < 4; ++m) {
          int l = l0 + i0 + m + t - 1;
          As[i0 + m][cc] = (l >= 0 && l < kW) ? p[l] : 0.f;
        }
      }
      {
        int cc = tid >> 4, j4 = (tid & 15) * 4;
        float4 v = *reinterpret_cast<const float4*>(
            wt + ((size_t)t * kC + c0 + cc) * Cout + o0 + j4);
        Bs[cc][j4 + 0] = v.x;
        Bs[cc][j4 + 1] = v.y;
        Bs[cc][j4 + 2] = v.z;
        Bs[cc][j4 + 3] = v.w;
      }
      __syncthreads();
#pragma unroll
      for (int kk = 0; kk < 16; ++kk) {
        float a[4], bv[4];
#pragma unroll
        for (int m = 0; m < 4; ++m) a[m] = As[ty * 4 + m][kk];
#pragma unroll
        for (int nn = 0; nn < 4; ++nn) bv[nn] = Bs[kk][tx * 4 + nn];
#pragma unroll
        for (int m = 0; m < 4; ++m)
#pragma unroll
          for (int nn = 0; nn < 4; ++nn) acc[m][nn] += a[m] * bv[nn];
      }
      __syncthreads();
    }
  }
#pragma unroll
  for (int nn = 0; nn < 4; ++nn) {
    int o = o0 + tx * 4 + nn;
    int hh = o / Eh, e = o - hh * Eh;
    float bsv = bias[o];
#pragma unroll
    for (int m = 0; m < 4; ++m) {
      int l = l0 + ty * 4 + m;
      out[(((size_t)n * 2 + hh) * kW + l) * Eh + e] = acc[m][nn] + bsv;
    }
  }
}

// ---------------- banded attention ---------------------------------------------------
// DIR=0 (left):  query i attends j in [i, i+64].  DIR=1 (right): j in [i-64, i].
template <int DIR>
__global__ void __launch_bounds__(256) attn_kernel(
    const float* __restrict__ Qb, const float* __restrict__ Kb,
    const float* __restrict__ Vb, float* __restrict__ Aout,
    float* __restrict__ Ob) {
  int qb = blockIdx.x;
  int nh = blockIdx.y;
  int n = nh >> 1, h = nh & 1;
  int q0 = qb * 64;
  int k_start = (DIR == 0) ? q0 : (q0 >= 64 ? q0 - 64 : 0);
  int k_end = (DIR == 0) ? (q0 + 128 < kW ? q0 + 128 : kW) : (q0 + 64);
  int kn = k_end - k_start;
  __shared__ float Qs[64][68];
  __shared__ float KP[128 * 68];  // K tile [k][68]; later reused as P [q][132]
  int tid = threadIdx.x;
  {
    int row = tid >> 2, cb = (tid & 3) * 16;
    const float* src = Qb + ((size_t)nh * kW + q0 + row) * 64 + cb;
    float* dst = &Qs[row][cb];
#pragma unroll
    for (int j = 0; j < 4; ++j)
      *reinterpret_cast<float4*>(dst + 4 * j) =
          *reinterpret_cast<const float4*>(src + 4 * j);
  }
#pragma unroll
  for (int rep = 0; rep < 2; ++rep) {
    int row = (tid >> 2) + rep * 64;
    int cb = (tid & 3) * 16;
    if (row < kn) {
      const float* src = Kb + ((size_t)nh * kW + k_start + row) * 64 + cb;
      float* dst = &KP[row * 68 + cb];
#pragma unroll
      for (int j = 0; j < 4; ++j)
        *reinterpret_cast<float4*>(dst + 4 * j) =
            *reinterpret_cast<const float4*>(src + 4 * j);
    }
  }
  __syncthreads();
  int q = tid >> 2, s = tid & 3;
  int gi = q0 + q;
  float sreg[32];
  float mx = -INFINITY;
#pragma unroll
  for (int u = 0; u < 32; ++u) {
    int ks = s * 32 + u;
    float val = -INFINITY;
    if (ks < kn) {
      int j = k_start + ks;
      bool valid = (DIR == 0) ? (j >= gi && j - gi <= 64) : (j <= gi && gi - j <= 64);
      if (valid) {
        const float* qrow = &Qs[q][0];
        const float* krow = &KP[ks * 68];
        float dot = 0.f;
#pragma unroll
        for (int e = 0; e < 64; ++e) dot += qrow[e] * krow[e];
        val = dot * 0.125f;
      }
    }
    sreg[u] = val;
    mx = fmaxf(mx, val);
  }
  mx = fmaxf(mx, __shfl_xor(mx, 1, 4));
  mx = fmaxf(mx, __shfl_xor(mx, 2, 4));
  float ssum = 0.f;
#pragma unroll
  for (int u = 0; u < 32; ++u) {
    float e = expf(sreg[u] - mx);  // exp(-inf)=0 for masked
    sreg[u] = e;
    ssum += e;
  }
  ssum += __shfl_xor(ssum, 1, 4);
  ssum += __shfl_xor(ssum, 2, 4);
  float inv = 1.f / ssum;
  __syncthreads();  // all K reads done; KP becomes P
  {
    float* arow = Aout + ((size_t)nh * kW + gi) * kW + k_start;
#pragma unroll
    for (int u = 0; u < 32; ++u) {
      int ks = s * 32 + u;
      if (ks < kn) {
        float p = sreg[u] * inv;
        p = (p > 0.01f) ? p : 0.f;  // A * (A > THR)
        KP[q * 132 + ks] = p;
        arow[ks] = p;
      }
    }
  }
  __syncthreads();
  float acc[24];
#pragma unroll
  for (int i = 0; i < 24; ++i) acc[i] = 0.f;
  const float* vbase = Vb + ((size_t)nh * kW + k_start) * 96 + s;
  for (int k = 0; k < kn; ++k) {
    float p = KP[q * 132 + k];
    if (p != 0.f) {
      const float* vr = vbase + (size_t)k * 96;
#pragma unroll
      for (int i = 0; i < 24; ++i) acc[i] += p * vr[4 * i];
    }
  }
  float* orow = Ob + ((size_t)n * kW + gi) * kC + h * 96 + s;
#pragma unroll
  for (int i = 0; i < 24; ++i) orow[4 * i] = acc[i];
}

// ---------------- out-projection + residual: lo[n][o][l] = raw + O@wo^T + bo ----------
__global__ void __launch_bounds__(256) proj_gemm(
    const float* __restrict__ wo, const float* __restrict__ Osrc,
    const float* __restrict__ bias, const float* __restrict__ raw,
    float* __restrict__ lo) {
  int l0 = blockIdx.x * 64;
  int o0 = blockIdx.y * 64;
  int n = blockIdx.z;
  int bb = n / kHH, h = n % kHH;
  __shared__ float As[64][17];  // [o][d-chunk]
  __shared__ float Bs[16][68];  // [d][l]
  int tid = threadIdx.x;
  int ty = tid >> 4, tx = tid & 15;
  float acc[4][4] = {};
  for (int c0 = 0; c0 < kC; c0 += 16) {
    {
      int i = tid >> 2, q = tid & 3;
      float4 v = *reinterpret_cast<const float4*>(wo + ((size_t)(o0 + i)) * kC + c0 + q * 4);
      As[i][q * 4 + 0] = v.x;
      As[i][q * 4 + 1] = v.y;
      As[i][q * 4 + 2] = v.z;
      As[i][q * 4 + 3] = v.w;
    }
    {
      int ll = tid >> 2, q = tid & 3;
      float4 v = *reinterpret_cast<const float4*>(
          Osrc + ((size_t)n * kW + l0 + ll) * kC + c0 + q * 4);
      Bs[q * 4 + 0][ll] = v.x;
      Bs[q * 4 + 1][ll] = v.y;
      Bs[q * 4 + 2][ll] = v.z;
      Bs[q * 4 + 3][ll] = v.w;
    }
    __syncthreads();
#pragma unroll
    for (int kk = 0; kk < 16; ++kk) {
      float a[4], bv[4];
#pragma unroll
      for (int m = 0; m < 4; ++m) a[m] = As[ty * 4 + m][kk];
#pragma unroll
      for (int nn = 0; nn < 4; ++nn) bv[nn] = Bs[kk][tx * 4 + nn];
#pragma unroll
      for (int m = 0; m < 4; ++m)
#pragma unroll
        for (int nn = 0; nn < 4; ++nn) acc[m][nn] += a[m] * bv[nn];
    }
    __syncthreads();
  }
#pragma unroll
  for (int m = 0; m < 4; ++m) {
    int o = o0 + ty * 4 + m;
    float4 rv = *reinterpret_cast<const float4*>(
        raw + (((size_t)bb * kC + o) * kHH + h) * kW + l0 + tx * 4);
    float bsv = bias[o];
    float4 ov;
    ov.x = acc[m][0] + bsv + rv.x;
    ov.y = acc[m][1] + bsv + rv.y;
    ov.z = acc[m][2] + bsv + rv.z;
    ov.w = acc[m][3] + bsv + rv.w;
    *reinterpret_cast<float4*>(lo + ((size_t)n * kC + o) * kW + l0 + tx * 4) = ov;
  }
}

// ---------------- FF + residual + transpose-out: out[b,c,h,w] = lo + lo@fw^T + fb -----
__global__ void __launch_bounds__(256) ff_gemm(
    const float* __restrict__ fw, const float* __restrict__ lo,
    const float* __restrict__ bias, float* __restrict__ outb) {
  int l0 = blockIdx.x * 64;
  int o0 = blockIdx.y * 64;
  int n = blockIdx.z;
  int bb = n / kHH, h = n % kHH;
  __shared__ float As[64][17];  // [o][d]
  __shared__ float Bs[16][68];  // [d][l]
  int tid = threadIdx.x;
  int ty = tid >> 4, tx = tid & 15;
  float acc[4][4] = {};
  for (int c0 = 0; c0 < kC; c0 += 16) {
    {
      int i = tid >> 2, q = tid & 3;
      float4 v = *reinterpret_cast<const float4*>(fw + ((size_t)(o0 + i)) * kC + c0 + q * 4);
      As[i][q * 4 + 0] = v.x;
      As[i][q * 4 + 1] = v.y;
      As[i][q * 4 + 2] = v.z;
      As[i][q * 4 + 3] = v.w;
    }
    {
      int cc = tid >> 4, ll4 = (tid & 15) * 4;
      float4 v = *reinterpret_cast<const float4*>(
          lo + ((size_t)n * kC + c0 + cc) * kW + l0 + ll4);
      Bs[cc][ll4 + 0] = v.x;
      Bs[cc][ll4 + 1] = v.y;
      Bs[cc][ll4 + 2] = v.z;
      Bs[cc][ll4 + 3] = v.w;
    }
    __syncthreads();
#pragma unroll
    for (int kk = 0; kk < 16; ++kk) {
      float a[4], bv[4];
#pragma unroll
      for (int m = 0; m < 4; ++m) a[m] = As[ty * 4 + m][kk];
#pragma unroll
      for (int nn = 0; nn < 4; ++nn) bv[nn] = Bs[kk][tx * 4 + nn];
#pragma unroll
      for (int m = 0; m < 4; ++m)
#pragma unroll
        for (int nn = 0; nn < 4; ++nn) acc[m][nn] += a[m] * bv[nn];
    }
    __syncthreads();
  }
#pragma unroll
  for (int m = 0; m < 4; ++m) {
    int o = o0 + ty * 4 + m;
    float4 rv = *reinterpret_cast<const float4*>(
        lo + ((size_t)n * kC + o) * kW + l0 + tx * 4);
    float bsv = bias[o];
    float4 ov;
    ov.x = acc[m][0] + bsv + rv.x;
    ov.y = acc[m][1] + bsv + rv.y;
    ov.z = acc[m][2] + bsv + rv.z;
    ov.w = acc[m][3] + bsv + rv.w;
    *reinterpret_cast<float4*>(outb + (((size_t)bb * kC + o) * kHH + h) * kW + l0 + tx * 4) = ov;
  }
}

extern "C" void kernel_launch(void* const* d_in, const int* in_sizes, int n_in,
                              void* d_out, int out_size, void* d_ws, size_t ws_size,
                              hipStream_t stream) {
  const float* l = (const float*)d_in[0];
  const float* r = (const float*)d_in[1];
  const float* lng[2] = {(const float*)d_in[2], (const float*)d_in[4]};
  const float* lnb[2] = {(const float*)d_in[3], (const float*)d_in[5]};
  const float* wq[2] = {(const float*)d_in[6], (const float*)d_in[14]};
  const float* bq[2] = {(const float*)d_in[7], (const float*)d_in[15]};
  const float* wk[2] = {(const float*)d_in[8], (const float*)d_in[16]};
  const float* bk[2] = {(const float*)d_in[9], (const float*)d_in[17]};
  const float* wv[2] = {(const float*)d_in[10], (const float*)d_in[18]};
  const float* bv[2] = {(const float*)d_in[11], (const float*)d_in[19]};
  const float* wo[2] = {(const float*)d_in[12], (const float*)d_in[20]};
  const float* bo[2] = {(const float*)d_in[13], (const float*)d_in[21]};
  const float* fw[2] = {(const float*)d_in[22], (const float*)d_in[24]};
  const float* fb[2] = {(const float*)d_in[23], (const float*)d_in[25]};
  float* out = (float*)d_out;
  float* ws = (float*)d_ws;

  float* lnbuf = ws;                           // 96*512*192
  float* rnbuf = lnbuf + (size_t)9437184;      // 96*512*192
  float* Qbuf  = rnbuf + (size_t)9437184;      // 96*2*512*64
  float* Kbuf  = Qbuf + (size_t)6291456;
  float* Vbuf  = Kbuf + (size_t)6291456;       // 96*2*512*96
  float* Obuf  = Vbuf + (size_t)9437184;       // 96*512*192
  float* lobuf = Obuf + (size_t)9437184;       // 96*192*512 (note [n][c][l] layout)
  float* wqT   = lobuf + (size_t)9437184;      // 3*192*128
  float* wkT   = wqT + 73728;
  float* wvT   = wkT + 73728;                  // 3*192*192

  ln_kernel<<<dim3(8, 96), 256, 0, stream>>>(l, lng[0], lnb[0], lnbuf);
  ln_kernel<<<dim3(8, 96), 256, 0, stream>>>(r, lng[1], lnb[1], rnbuf);
  // zero both A outputs (band kernel only writes 128 cols per row)
  hipMemsetAsync(out + (size_t)18874368, 0, (size_t)402653184, stream);

  for (int dir = 0; dir < 2; ++dir) {
    const float* qin = dir == 0 ? lnbuf : rnbuf;
    const float* kin = dir == 0 ? rnbuf : lnbuf;
    const float* vraw = dir == 0 ? r : l;
    const float* resraw = dir == 0 ? l : r;
    float* Aout = out + (dir == 0 ? (size_t)18874368 : (size_t)69206016);
    float* outb = out + (dir == 0 ? (size_t)0 : (size_t)9437184);

    wprep_conv<<<(73728 + 255) / 256, 256, 0, stream>>>(wq[dir], wqT, 73728, 128);
    wprep_conv<<<(73728 + 255) / 256, 256, 0, stream>>>(wk[dir], wkT, 73728, 128);
    wprep_conv<<<(110592 + 255) / 256, 256, 0, stream>>>(wv[dir], wvT, 110592, 192);

    conv_gemm<false><<<dim3(8, 2, 96), 256, 0, stream>>>(qin, wqT, bq[dir], Qbuf, 128, 64);
    conv_gemm<false><<<dim3(8, 2, 96), 256, 0, stream>>>(kin, wkT, bk[dir], Kbuf, 128, 64);
    conv_gemm<true><<<dim3(8, 3, 96), 256, 0, stream>>>(vraw, wvT, bv[dir], Vbuf, 192, 96);

    if (dir == 0)
      attn_kernel<0><<<dim3(8, 192), 256, 0, stream>>>(Qbuf, Kbuf, Vbuf, Aout, Obuf);
    else
      attn_kernel<1><<<dim3(8, 192), 256, 0, stream>>>(Qbuf, Kbuf, Vbuf, Aout, Obuf);

    proj_gemm<<<dim3(8, 3, 96), 256, 0, stream>>>(wo[dir], Obuf, bo[dir], resraw, lobuf);
    ff_gemm<<<dim3(8, 3, 96), 256, 0, stream>>>(fw[dir], lobuf, fb[dir], outb);
  }
}

// Round 2
// 1014.451 us; speedup vs baseline: 1.6578x; 1.6578x over previous
//
#include <hip/hip_runtime.h>
#include <cstddef>
#include <cstdint>

constexpr int kC = 192;    // channels
constexpr int kW = 512;    // sequence length (width)
constexpr int kHH = 48;    // H

typedef unsigned short u16;
typedef __attribute__((ext_vector_type(8))) short bf16x8;
typedef __attribute__((ext_vector_type(4))) float f32x4;
typedef __attribute__((ext_vector_type(4))) unsigned short us4;

__device__ inline u16 f2bf(float f) {
  union { float f; uint32_t u; } v; v.f = f;
  uint32_t r = v.u + 0x7FFF + ((v.u >> 16) & 1);  // RNE
  return (u16)(r >> 16);
}
__device__ inline float bf2f(u16 u) {
  return __uint_as_float(((uint32_t)u) << 16);
}

// ---------------- LayerNorm + transpose + bf16 cast ----------------------------------
// x[b,c,h,w] -> lnout bf16 [n,w,c] (normalized), rawout bf16 [n,w,c] (just transposed)
__global__ void __launch_bounds__(256) ln_kernel(
    const float* __restrict__ x, const float* __restrict__ g,
    const float* __restrict__ b, u16* __restrict__ lnout, u16* __restrict__ rawout) {
  int n = blockIdx.y;
  int w0 = blockIdx.x * 64;
  int bb = n / kHH, h = n % kHH;
  __shared__ float tile[64][193];
  __shared__ float red[8][64];
  __shared__ float mean_s[64], rstd_s[64];
  int tid = threadIdx.x;
  int lane = tid & 63, wv = tid >> 6;
  for (int c = wv; c < kC; c += 4) {
    tile[lane][c] = x[(((size_t)bb * kC + c) * kHH + h) * kW + w0 + lane];
  }
  __syncthreads();
  {
    int w = tid & 63, part = tid >> 6;
    float s = 0.f, s2 = 0.f;
    const float* row = &tile[w][0];
    for (int c = part * 48; c < part * 48 + 48; ++c) {
      float v = row[c];
      s += v; s2 += v * v;
    }
    red[part][w] = s;
    red[part + 4][w] = s2;
  }
  __syncthreads();
  if (tid < 64) {
    float s = red[0][tid] + red[1][tid] + red[2][tid] + red[3][tid];
    float s2 = red[4][tid] + red[5][tid] + red[6][tid] + red[7][tid];
    float m = s * (1.f / 192.f);
    float var = s2 * (1.f / 192.f) - m * m;
    mean_s[tid] = m;
    rstd_s[tid] = rsqrtf(var + 1e-5f);
  }
  __syncthreads();
  for (int e = tid; e < 64 * kC; e += 256) {
    int w = e / kC, c = e % kC;
    float raw = tile[w][c];
    float ln = (raw - mean_s[w]) * rstd_s[w] * g[c] + b[c];
    size_t idx = ((size_t)n * kW + w0 + w) * kC + c;
    lnout[idx] = f2bf(ln);
    rawout[idx] = f2bf(raw);
  }
}

// ---------------- conv weight prep: w[o][c][t] fp32 -> w2[o][t*192+c] bf16 -----------
__global__ void wprep_bf16(const float* __restrict__ w, u16* __restrict__ w2, int total) {
  int idx = blockIdx.x * 256 + threadIdx.x;
  if (idx >= total) return;
  int o = idx / 576, k = idx % 576;
  int t = k / 192, c = k % 192;
  w2[idx] = f2bf(w[((size_t)o * kC + c) * 3 + t]);
}

// ---------------- conv1d(k=3) as bf16 MFMA GEMM --------------------------------------
// in: bf16 [n][512][192]; w2: bf16 [Cout][576] (k = t*192+c)
// out: fp32 [(n*2+hh)][512][EH], hh = o/EH
template <int EH>
__global__ void __launch_bounds__(256) conv_mfma(
    const u16* __restrict__ in, const u16* __restrict__ w2,
    const float* __restrict__ bias, float* __restrict__ out) {
  int l0 = blockIdx.x * 64;
  int o0 = blockIdx.y * 64;
  int n = blockIdx.z;
  __shared__ __attribute__((aligned(16))) u16 As[66][72];
  __shared__ __attribute__((aligned(16))) u16 Bs[3][64][72];
  int tid = threadIdx.x;
  int wid = tid >> 6, lane = tid & 63;
  int wm = wid >> 1, wn = wid & 1;
  int lr = lane & 15, lk = (lane >> 4) * 8;
  f32x4 acc[2][2] = {};
  for (int c0 = 0; c0 < kC; c0 += 64) {
    // stage A: rows l0-1 .. l0+64 (66 rows), channels c0..c0+63
    for (int u = tid; u < 66 * 16; u += 256) {
      int row = u >> 4, q = u & 15;
      int l = l0 - 1 + row;
      us4 v = {0, 0, 0, 0};
      if (l >= 0 && l < kW)
        v = *reinterpret_cast<const us4*>(in + ((size_t)n * kW + l) * kC + c0 + q * 4);
      *reinterpret_cast<us4*>(&As[row][q * 4]) = v;
    }
    // stage B: 3 taps x [64 o][64 k]
    for (int u = tid; u < 3 * 64 * 16; u += 256) {
      int t = u >> 10;
      int rem = u & 1023;
      int o = rem >> 4, q = rem & 15;
      us4 v = *reinterpret_cast<const us4*>(
          w2 + (size_t)(o0 + o) * 576 + t * kC + c0 + q * 4);
      *reinterpret_cast<us4*>(&Bs[t][o][q * 4]) = v;
    }
    __syncthreads();
#pragma unroll
    for (int t = 0; t < 3; ++t) {
#pragma unroll
      for (int ks = 0; ks < 2; ++ks) {
        bf16x8 a[2], b[2];
#pragma unroll
        for (int m2 = 0; m2 < 2; ++m2)
          a[m2] = *reinterpret_cast<const bf16x8*>(&As[wm * 32 + m2 * 16 + lr + t][ks * 32 + lk]);
#pragma unroll
        for (int n2 = 0; n2 < 2; ++n2)
          b[n2] = *reinterpret_cast<const bf16x8*>(&Bs[t][wn * 32 + n2 * 16 + lr][ks * 32 + lk]);
#pragma unroll
        for (int m2 = 0; m2 < 2; ++m2)
#pragma unroll
          for (int n2 = 0; n2 < 2; ++n2)
            acc[m2][n2] = __builtin_amdgcn_mfma_f32_16x16x32_bf16(a[m2], b[n2], acc[m2][n2], 0, 0, 0);
      }
    }
    __syncthreads();
  }
  int lg = lane >> 4;
#pragma unroll
  for (int n2 = 0; n2 < 2; ++n2) {
    int o = o0 + wn * 32 + n2 * 16 + lr;
    int hh = o / EH, e = o - hh * EH;
    float bsv = bias[o];
#pragma unroll
    for (int m2 = 0; m2 < 2; ++m2) {
#pragma unroll
      for (int rg = 0; rg < 4; ++rg) {
        int l = l0 + wm * 32 + m2 * 16 + lg * 4 + rg;
        out[(((size_t)n * 2 + hh) * kW + l) * EH + e] = acc[m2][n2][rg] + bsv;
      }
    }
  }
}

// ---------------- banded attention (fp32, unchanged) ---------------------------------
template <int DIR>
__global__ void __launch_bounds__(256) attn_kernel(
    const float* __restrict__ Qb, const float* __restrict__ Kb,
    const float* __restrict__ Vb, float* __restrict__ Aout,
    float* __restrict__ Ob) {
  int qb = blockIdx.x;
  int nh = blockIdx.y;
  int n = nh >> 1, h = nh & 1;
  int q0 = qb * 64;
  int k_start = (DIR == 0) ? q0 : (q0 >= 64 ? q0 - 64 : 0);
  int k_end = (DIR == 0) ? (q0 + 128 < kW ? q0 + 128 : kW) : (q0 + 64);
  int kn = k_end - k_start;
  __shared__ float Qs[64][68];
  __shared__ float KP[128 * 68];
  int tid = threadIdx.x;
  {
    int row = tid >> 2, cb = (tid & 3) * 16;
    const float* src = Qb + ((size_t)nh * kW + q0 + row) * 64 + cb;
    float* dst = &Qs[row][cb];
#pragma unroll
    for (int j = 0; j < 4; ++j)
      *reinterpret_cast<float4*>(dst + 4 * j) =
          *reinterpret_cast<const float4*>(src + 4 * j);
  }
#pragma unroll
  for (int rep = 0; rep < 2; ++rep) {
    int row = (tid >> 2) + rep * 64;
    int cb = (tid & 3) * 16;
    if (row < kn) {
      const float* src = Kb + ((size_t)nh * kW + k_start + row) * 64 + cb;
      float* dst = &KP[row * 68 + cb];
#pragma unroll
      for (int j = 0; j < 4; ++j)
        *reinterpret_cast<float4*>(dst + 4 * j) =
            *reinterpret_cast<const float4*>(src + 4 * j);
    }
  }
  __syncthreads();
  int q = tid >> 2, s = tid & 3;
  int gi = q0 + q;
  float sreg[32];
  float mx = -INFINITY;
#pragma unroll
  for (int u = 0; u < 32; ++u) {
    int ks = s * 32 + u;
    float val = -INFINITY;
    if (ks < kn) {
      int j = k_start + ks;
      bool valid = (DIR == 0) ? (j >= gi && j - gi <= 64) : (j <= gi && gi - j <= 64);
      if (valid) {
        const float* qrow = &Qs[q][0];
        const float* krow = &KP[ks * 68];
        float dot = 0.f;
#pragma unroll
        for (int e = 0; e < 64; ++e) dot += qrow[e] * krow[e];
        val = dot * 0.125f;
      }
    }
    sreg[u] = val;
    mx = fmaxf(mx, val);
  }
  mx = fmaxf(mx, __shfl_xor(mx, 1, 4));
  mx = fmaxf(mx, __shfl_xor(mx, 2, 4));
  float ssum = 0.f;
#pragma unroll
  for (int u = 0; u < 32; ++u) {
    float e = expf(sreg[u] - mx);
    sreg[u] = e;
    ssum += e;
  }
  ssum += __shfl_xor(ssum, 1, 4);
  ssum += __shfl_xor(ssum, 2, 4);
  float inv = 1.f / ssum;
  __syncthreads();
  {
    float* arow = Aout + ((size_t)nh * kW + gi) * kW + k_start;
#pragma unroll
    for (int u = 0; u < 32; ++u) {
      int ks = s * 32 + u;
      if (ks < kn) {
        float p = sreg[u] * inv;
        p = (p > 0.01f) ? p : 0.f;
        KP[q * 132 + ks] = p;
        arow[ks] = p;
      }
    }
  }
  __syncthreads();
  float acc[24];
#pragma unroll
  for (int i = 0; i < 24; ++i) acc[i] = 0.f;
  const float* vbase = Vb + ((size_t)nh * kW + k_start) * 96 + s;
  for (int k = 0; k < kn; ++k) {
    float p = KP[q * 132 + k];
    if (p != 0.f) {
      const float* vr = vbase + (size_t)k * 96;
#pragma unroll
      for (int i = 0; i < 24; ++i) acc[i] += p * vr[4 * i];
    }
  }
  float* orow = Ob + ((size_t)n * kW + gi) * kC + h * 96 + s;
#pragma unroll
  for (int i = 0; i < 24; ++i) orow[4 * i] = acc[i];
}

// ---------------- out-projection (bf16 MFMA) + residual -------------------------------
// lo[l][o] = O[l][:] @ wo[o][:] + bo + raw_bf[l][o]; writes fp32 + bf16 copies [n][l][192]
__global__ void __launch_bounds__(256) proj_mfma(
    const float* __restrict__ wo, const float* __restrict__ Osrc,
    const float* __restrict__ bias, const u16* __restrict__ resbf,
    float* __restrict__ lof, u16* __restrict__ lobf) {
  int l0 = blockIdx.x * 64;
  int o0 = blockIdx.y * 64;
  int n = blockIdx.z;
  __shared__ __attribute__((aligned(16))) u16 As[64][72];
  __shared__ __attribute__((aligned(16))) u16 Bs[64][72];
  int tid = threadIdx.x;
  int wid = tid >> 6, lane = tid & 63;
  int wm = wid >> 1, wn = wid & 1;
  int lr = lane & 15, lk = (lane >> 4) * 8;
  f32x4 acc[2][2] = {};
  for (int c0 = 0; c0 < kC; c0 += 64) {
    for (int u = tid; u < 64 * 16; u += 256) {
      int row = u >> 4, q = u & 15;
      float4 v = *reinterpret_cast<const float4*>(
          Osrc + ((size_t)n * kW + l0 + row) * kC + c0 + q * 4);
      us4 h = {f2bf(v.x), f2bf(v.y), f2bf(v.z), f2bf(v.w)};
      *reinterpret_cast<us4*>(&As[row][q * 4]) = h;
    }
    for (int u = tid; u < 64 * 16; u += 256) {
      int o = u >> 4, q = u & 15;
      float4 v = *reinterpret_cast<const float4*>(
          wo + (size_t)(o0 + o) * kC + c0 + q * 4);
      us4 h = {f2bf(v.x), f2bf(v.y), f2bf(v.z), f2bf(v.w)};
      *reinterpret_cast<us4*>(&Bs[o][q * 4]) = h;
    }
    __syncthreads();
#pragma unroll
    for (int ks = 0; ks < 2; ++ks) {
      bf16x8 a[2], b[2];
#pragma unroll
      for (int m2 = 0; m2 < 2; ++m2)
        a[m2] = *reinterpret_cast<const bf16x8*>(&As[wm * 32 + m2 * 16 + lr][ks * 32 + lk]);
#pragma unroll
      for (int n2 = 0; n2 < 2; ++n2)
        b[n2] = *reinterpret_cast<const bf16x8*>(&Bs[wn * 32 + n2 * 16 + lr][ks * 32 + lk]);
#pragma unroll
      for (int m2 = 0; m2 < 2; ++m2)
#pragma unroll
        for (int n2 = 0; n2 < 2; ++n2)
          acc[m2][n2] = __builtin_amdgcn_mfma_f32_16x16x32_bf16(a[m2], b[n2], acc[m2][n2], 0, 0, 0);
    }
    __syncthreads();
  }
  int lg = lane >> 4;
#pragma unroll
  for (int n2 = 0; n2 < 2; ++n2) {
    int o = o0 + wn * 32 + n2 * 16 + lr;
    float bsv = bias[o];
#pragma unroll
    for (int m2 = 0; m2 < 2; ++m2) {
#pragma unroll
      for (int rg = 0; rg < 4; ++rg) {
        int l = l0 + wm * 32 + m2 * 16 + lg * 4 + rg;
        size_t idx = ((size_t)n * kW + l) * kC + o;
        float v = acc[m2][n2][rg] + bsv + bf2f(resbf[idx]);
        lof[idx] = v;
        lobf[idx] = f2bf(v);
      }
    }
  }
}

// ---------------- FF (bf16 MFMA) + residual + transpose to [b,c,h,w] -----------------
__global__ void __launch_bounds__(256) ff_mfma(
    const float* __restrict__ fw, const u16* __restrict__ lobf,
    const float* __restrict__ bias, const float* __restrict__ lof,
    float* __restrict__ outb) {
  int l0 = blockIdx.x * 64;
  int o0 = blockIdx.y * 64;
  int n = blockIdx.z;
  int bb = n / kHH, h = n % kHH;
  __shared__ __attribute__((aligned(16))) u16 As[64][72];
  __shared__ __attribute__((aligned(16))) u16 Bs[64][72];
  int tid = threadIdx.x;
  int wid = tid >> 6, lane = tid & 63;
  int wm = wid >> 1, wn = wid & 1;
  int lr = lane & 15, lk = (lane >> 4) * 8;
  f32x4 acc[2][2] = {};
  for (int c0 = 0; c0 < kC; c0 += 64) {
    for (int u = tid; u < 64 * 16; u += 256) {
      int row = u >> 4, q = u & 15;
      us4 v = *reinterpret_cast<const us4*>(
          lobf + ((size_t)n * kW + l0 + row) * kC + c0 + q * 4);
      *reinterpret_cast<us4*>(&As[row][q * 4]) = v;
    }
    for (int u = tid; u < 64 * 16; u += 256) {
      int o = u >> 4, q = u & 15;
      float4 v = *reinterpret_cast<const float4*>(
          fw + (size_t)(o0 + o) * kC + c0 + q * 4);
      us4 h = {f2bf(v.x), f2bf(v.y), f2bf(v.z), f2bf(v.w)};
      *reinterpret_cast<us4*>(&Bs[o][q * 4]) = h;
    }
    __syncthreads();
#pragma unroll
    for (int ks = 0; ks < 2; ++ks) {
      bf16x8 a[2], b[2];
#pragma unroll
      for (int m2 = 0; m2 < 2; ++m2)
        a[m2] = *reinterpret_cast<const bf16x8*>(&As[wm * 32 + m2 * 16 + lr][ks * 32 + lk]);
#pragma unroll
      for (int n2 = 0; n2 < 2; ++n2)
        b[n2] = *reinterpret_cast<const bf16x8*>(&Bs[wn * 32 + n2 * 16 + lr][ks * 32 + lk]);
#pragma unroll
      for (int m2 = 0; m2 < 2; ++m2)
#pragma unroll
        for (int n2 = 0; n2 < 2; ++n2)
          acc[m2][n2] = __builtin_amdgcn_mfma_f32_16x16x32_bf16(a[m2], b[n2], acc[m2][n2], 0, 0, 0);
    }
    __syncthreads();
  }
  int lg = lane >> 4;
#pragma unroll
  for (int n2 = 0; n2 < 2; ++n2) {
    int o = o0 + wn * 32 + n2 * 16 + lr;
    float bsv = bias[o];
#pragma unroll
    for (int m2 = 0; m2 < 2; ++m2) {
#pragma unroll
      for (int rg = 0; rg < 4; ++rg) {
        int l = l0 + wm * 32 + m2 * 16 + lg * 4 + rg;
        float res = lof[((size_t)n * kW + l) * kC + o];
        outb[(((size_t)bb * kC + o) * kHH + h) * kW + l] = acc[m2][n2][rg] + bsv + res;
      }
    }
  }
}

extern "C" void kernel_launch(void* const* d_in, const int* in_sizes, int n_in,
                              void* d_out, int out_size, void* d_ws, size_t ws_size,
                              hipStream_t stream) {
  const float* l = (const float*)d_in[0];
  const float* r = (const float*)d_in[1];
  const float* lng[2] = {(const float*)d_in[2], (const float*)d_in[4]};
  const float* lnb[2] = {(const float*)d_in[3], (const float*)d_in[5]};
  const float* wq[2] = {(const float*)d_in[6], (const float*)d_in[14]};
  const float* bq[2] = {(const float*)d_in[7], (const float*)d_in[15]};
  const float* wk[2] = {(const float*)d_in[8], (const float*)d_in[16]};
  const float* bk[2] = {(const float*)d_in[9], (const float*)d_in[17]};
  const float* wv[2] = {(const float*)d_in[10], (const float*)d_in[18]};
  const float* bv[2] = {(const float*)d_in[11], (const float*)d_in[19]};
  const float* wo[2] = {(const float*)d_in[12], (const float*)d_in[20]};
  const float* bo[2] = {(const float*)d_in[13], (const float*)d_in[21]};
  const float* fw[2] = {(const float*)d_in[22], (const float*)d_in[24]};
  const float* fb[2] = {(const float*)d_in[23], (const float*)d_in[25]};
  float* out = (float*)d_out;
  float* ws = (float*)d_ws;

  // workspace layout (float element offsets)
  u16* lnl_bf  = (u16*)(ws + 0);          // bf16 [96][512][192]
  u16* lnr_bf  = (u16*)(ws + 4718592);
  u16* lraw_bf = (u16*)(ws + 9437184);
  u16* rraw_bf = (u16*)(ws + 14155776);
  float* Qbuf  = ws + 18874368;           // fp32 [192][512][64]
  float* Kbuf  = ws + 25165824;
  float* Vbuf  = ws + 31457280;           // fp32 [192][512][96]
  float* Obuf  = ws + 40894464;           // fp32 [96][512][192]
  float* lof   = ws + 50331648;           // fp32 [96][512][192]
  u16* lobf    = (u16*)(ws + 59768832);   // bf16 [96][512][192]
  u16* wq2     = (u16*)(ws + 64487424);   // bf16 [128][576]
  u16* wk2     = (u16*)(ws + 64524288);
  u16* wv2     = (u16*)(ws + 64561152);   // bf16 [192][576]

  ln_kernel<<<dim3(8, 96), 256, 0, stream>>>(l, lng[0], lnb[0], lnl_bf, lraw_bf);
  ln_kernel<<<dim3(8, 96), 256, 0, stream>>>(r, lng[1], lnb[1], lnr_bf, rraw_bf);
  // zero both A outputs (band kernel only writes 128 cols per row)
  hipMemsetAsync(out + (size_t)18874368, 0, (size_t)402653184, stream);

  for (int dir = 0; dir < 2; ++dir) {
    const u16* qin = dir == 0 ? lnl_bf : lnr_bf;
    const u16* kin = dir == 0 ? lnr_bf : lnl_bf;
    const u16* vin = dir == 0 ? rraw_bf : lraw_bf;
    const u16* resbf = dir == 0 ? lraw_bf : rraw_bf;
    float* Aout = out + (dir == 0 ? (size_t)18874368 : (size_t)69206016);
    float* outb = out + (dir == 0 ? (size_t)0 : (size_t)9437184);

    wprep_bf16<<<(73728 + 255) / 256, 256, 0, stream>>>(wq[dir], wq2, 73728);
    wprep_bf16<<<(73728 + 255) / 256, 256, 0, stream>>>(wk[dir], wk2, 73728);
    wprep_bf16<<<(110592 + 255) / 256, 256, 0, stream>>>(wv[dir], wv2, 110592);

    conv_mfma<64><<<dim3(8, 2, 96), 256, 0, stream>>>(qin, wq2, bq[dir], Qbuf);
    conv_mfma<64><<<dim3(8, 2, 96), 256, 0, stream>>>(kin, wk2, bk[dir], Kbuf);
    conv_mfma<96><<<dim3(8, 3, 96), 256, 0, stream>>>(vin, wv2, bv[dir], Vbuf);

    if (dir == 0)
      attn_kernel<0><<<dim3(8, 192), 256, 0, stream>>>(Qbuf, Kbuf, Vbuf, Aout, Obuf);
    else
      attn_kernel<1><<<dim3(8, 192), 256, 0, stream>>>(Qbuf, Kbuf, Vbuf, Aout, Obuf);

    proj_mfma<<<dim3(8, 3, 96), 256, 0, stream>>>(wo[dir], Obuf, bo[dir], resbf, lof, lobf);
    ff_mfma<<<dim3(8, 3, 96), 256, 0, stream>>>(fw[dir], lobf, fb[dir], lof, outb);
  }
}

// Round 3
// 582.168 us; speedup vs baseline: 2.8888x; 1.7425x over previous
//
#include <hip/hip_runtime.h>
#include <cstddef>
#include <cstdint>

constexpr int kC = 192;    // channels
constexpr int kW = 512;    // sequence length
constexpr int kHH = 48;    // H

typedef unsigned short u16;
typedef __attribute__((ext_vector_type(8))) short bf16x8;
typedef __attribute__((ext_vector_type(4))) float f32x4;
typedef __attribute__((ext_vector_type(4))) unsigned short us4;

__device__ inline u16 f2bf(float f) {
  union { float f; uint32_t u; } v; v.f = f;
  uint32_t r = v.u + 0x7FFF + ((v.u >> 16) & 1);  // RNE
  return (u16)(r >> 16);
}
__device__ inline float bf2f(u16 u) {
  return __uint_as_float(((uint32_t)u) << 16);
}

// ---------------- LayerNorm (both tensors, merged) ------------------------------------
// z=0: l -> lnl,lraw ; z=1: r -> lnr,rraw. out bf16 [n][w][192]
__global__ void __launch_bounds__(256) ln_kernel(
    const float* __restrict__ xl, const float* __restrict__ xr,
    const float* __restrict__ gl, const float* __restrict__ bl,
    const float* __restrict__ gr, const float* __restrict__ br,
    u16* __restrict__ lnl, u16* __restrict__ lraw,
    u16* __restrict__ lnr, u16* __restrict__ rraw) {
  int n = blockIdx.y;
  int w0 = blockIdx.x * 64;
  int side = blockIdx.z;
  const float* x = side ? xr : xl;
  const float* g = side ? gr : gl;
  const float* b = side ? br : bl;
  u16* lnout = side ? lnr : lnl;
  u16* rawout = side ? rraw : lraw;
  int bb = n / kHH, h = n % kHH;
  __shared__ float tile[64][193];
  __shared__ float red[8][64];
  __shared__ float mean_s[64], rstd_s[64];
  int tid = threadIdx.x;
  int lane = tid & 63, wv = tid >> 6;
  for (int c = wv; c < kC; c += 4)
    tile[lane][c] = x[(((size_t)bb * kC + c) * kHH + h) * kW + w0 + lane];
  __syncthreads();
  {
    int w = tid & 63, part = tid >> 6;
    float s = 0.f, s2 = 0.f;
    const float* row = &tile[w][0];
    for (int c = part * 48; c < part * 48 + 48; ++c) {
      float v = row[c];
      s += v; s2 += v * v;
    }
    red[part][w] = s;
    red[part + 4][w] = s2;
  }
  __syncthreads();
  if (tid < 64) {
    float s = red[0][tid] + red[1][tid] + red[2][tid] + red[3][tid];
    float s2 = red[4][tid] + red[5][tid] + red[6][tid] + red[7][tid];
    float m = s * (1.f / 192.f);
    float var = s2 * (1.f / 192.f) - m * m;
    mean_s[tid] = m;
    rstd_s[tid] = rsqrtf(var + 1e-5f);
  }
  __syncthreads();
  for (int u = tid; u < 64 * 48; u += 256) {
    int w = u / 48, c4 = (u % 48) * 4;
    float mm = mean_s[w], rs = rstd_s[w];
    us4 lp, rp;
#pragma unroll
    for (int j = 0; j < 4; ++j) {
      float raw = tile[w][c4 + j];
      rp[j] = f2bf(raw);
      lp[j] = f2bf((raw - mm) * rs * g[c4 + j] + b[c4 + j]);
    }
    size_t idx = ((size_t)n * kW + w0 + w) * kC + c4;
    *reinterpret_cast<us4*>(&lnout[idx]) = lp;
    *reinterpret_cast<us4*>(&rawout[idx]) = rp;
  }
}

// ---------------- weight prep (all 6 convs + biases) ----------------------------------
// wall per dir: [q 128*576][k 128*576][v 192*576], layout [o][t*192+c] bf16.
__global__ void wprep_all(
    const float* wq0, const float* wk0, const float* wv0,
    const float* wq1, const float* wk1, const float* wv1,
    const float* bq0, const float* bk0, const float* bv0,
    const float* bq1, const float* bk1, const float* bv1,
    u16* __restrict__ wall, float* __restrict__ ball) {
  int idx = blockIdx.x * 256 + threadIdx.x;
  if (idx < 516096) {
    int dir = idx / 258048, off = idx % 258048;
    const float* src; int soff;
    if (off < 73728) { src = dir ? wq1 : wq0; soff = off; }
    else if (off < 147456) { src = dir ? wk1 : wk0; soff = off - 73728; }
    else { src = dir ? wv1 : wv0; soff = off - 147456; }
    int o = soff / 576, k = soff % 576, t = k / 192, c = k % 192;
    wall[idx] = f2bf(src[((size_t)o * kC + c) * 3 + t]);
  } else if (idx < 516096 + 896) {
    int bi = idx - 516096;
    int dir = bi / 448, boff = bi % 448;
    const float* s; int so;
    if (boff < 128) { s = dir ? bq1 : bq0; so = boff; }
    else if (boff < 256) { s = dir ? bk1 : bk0; so = boff - 128; }
    else { s = dir ? bv1 : bv0; so = boff - 256; }
    ball[bi] = s[so];
  }
}

// ---------------- conv1d(k=3) bf16 MFMA, all 14 jobs in one launch --------------------
// Q/K out: bf16 [dir][nh][512][64]; V out: bf16 [dir][nh][96][512] (transposed)
__global__ void __launch_bounds__(256) conv_mfma_all(
    const u16* __restrict__ lnl, const u16* __restrict__ lnr,
    const u16* __restrict__ lraw, const u16* __restrict__ rraw,
    const u16* __restrict__ wall, const float* __restrict__ ball,
    u16* __restrict__ Qbf, u16* __restrict__ Kbf, u16* __restrict__ Vbf) {
  int l0 = blockIdx.x * 64;
  int jid = blockIdx.y;
  int n = blockIdx.z;
  int dir = jid / 7, j = jid % 7;
  int which = j < 2 ? 0 : (j < 4 ? 1 : 2);
  int o0 = (which == 0 ? j : which == 1 ? j - 2 : j - 4) * 64;
  const u16* in = which == 0 ? (dir ? lnr : lnl)
                : which == 1 ? (dir ? lnl : lnr)
                             : (dir ? lraw : rraw);
  const u16* w2 = wall + (size_t)dir * 258048 +
                  (which == 0 ? 0 : which == 1 ? 73728 : 147456);
  const float* bias = ball + dir * 448 + (which == 0 ? 0 : which == 1 ? 128 : 256);

  __shared__ __attribute__((aligned(16))) u16 As[66][72];
  __shared__ __attribute__((aligned(16))) u16 Bs[3][64][72];
  int tid = threadIdx.x;
  int wid = tid >> 6, lane = tid & 63;
  int wm = wid >> 1, wn = wid & 1;
  int lr = lane & 15, lk = (lane >> 4) * 8;
  f32x4 acc[2][2] = {};
  for (int c0 = 0; c0 < kC; c0 += 64) {
    for (int u = tid; u < 66 * 16; u += 256) {
      int row = u >> 4, q = u & 15;
      int l = l0 - 1 + row;
      us4 v = {0, 0, 0, 0};
      if (l >= 0 && l < kW)
        v = *reinterpret_cast<const us4*>(in + ((size_t)n * kW + l) * kC + c0 + q * 4);
      *reinterpret_cast<us4*>(&As[row][q * 4]) = v;
    }
    for (int u = tid; u < 3 * 64 * 16; u += 256) {
      int t = u >> 10;
      int rem = u & 1023;
      int o = rem >> 4, q = rem & 15;
      us4 v = *reinterpret_cast<const us4*>(
          w2 + (size_t)(o0 + o) * 576 + t * kC + c0 + q * 4);
      *reinterpret_cast<us4*>(&Bs[t][o][q * 4]) = v;
    }
    __syncthreads();
#pragma unroll
    for (int t = 0; t < 3; ++t) {
#pragma unroll
      for (int ks = 0; ks < 2; ++ks) {
        bf16x8 a[2], b[2];
#pragma unroll
        for (int m2 = 0; m2 < 2; ++m2)
          a[m2] = *reinterpret_cast<const bf16x8*>(&As[wm * 32 + m2 * 16 + lr + t][ks * 32 + lk]);
#pragma unroll
        for (int n2 = 0; n2 < 2; ++n2)
          b[n2] = *reinterpret_cast<const bf16x8*>(&Bs[t][wn * 32 + n2 * 16 + lr][ks * 32 + lk]);
#pragma unroll
        for (int m2 = 0; m2 < 2; ++m2)
#pragma unroll
          for (int n2 = 0; n2 < 2; ++n2)
            acc[m2][n2] = __builtin_amdgcn_mfma_f32_16x16x32_bf16(a[m2], b[n2], acc[m2][n2], 0, 0, 0);
      }
    }
    __syncthreads();
  }
  int lg = lane >> 4;
  if (which < 2) {
    u16* out = (which == 0 ? Qbf : Kbf) + (size_t)dir * 6291456;
#pragma unroll
    for (int n2 = 0; n2 < 2; ++n2) {
      int o = o0 + wn * 32 + n2 * 16 + lr;
      int hh = o >> 6, e = o & 63;
      float bsv = bias[o];
#pragma unroll
      for (int m2 = 0; m2 < 2; ++m2) {
#pragma unroll
        for (int rg = 0; rg < 4; ++rg) {
          int l = l0 + wm * 32 + m2 * 16 + lg * 4 + rg;
          out[((size_t)(n * 2 + hh) * kW + l) * 64 + e] = f2bf(acc[m2][n2][rg] + bsv);
        }
      }
    }
  } else {
    u16* out = Vbf + (size_t)dir * 9437184;
#pragma unroll
    for (int n2 = 0; n2 < 2; ++n2) {
      int o = o0 + wn * 32 + n2 * 16 + lr;
      int hh = o / 96, e = o - hh * 96;
      float bsv = bias[o];
#pragma unroll
      for (int m2 = 0; m2 < 2; ++m2) {
        int lb = l0 + wm * 32 + m2 * 16 + lg * 4;
        us4 p;
#pragma unroll
        for (int rg = 0; rg < 4; ++rg) p[rg] = f2bf(acc[m2][n2][rg] + bsv);
        *reinterpret_cast<us4*>(&out[((size_t)(n * 2 + hh) * 96 + e) * kW + lb]) = p;
      }
    }
  }
}

// ---------------- banded attention, bf16 MFMA, both dirs ------------------------------
// S^T = mfma(K,Q): lane holds q=wid*16+(l&15); k = kf*16+g*4+reg.
__global__ void __launch_bounds__(256) attn_mfma(
    const u16* __restrict__ Qbf, const u16* __restrict__ Kbf,
    const u16* __restrict__ Vbf, float* __restrict__ Abase,
    u16* __restrict__ Obf) {
  int qb = blockIdx.x;
  int nh = blockIdx.y;
  int dir = blockIdx.z;
  int q0 = qb * 64;
  int k_start = dir == 0 ? q0 : (q0 >= 64 ? q0 - 64 : 0);
  int k_end = dir == 0 ? (q0 + 128 <= kW ? q0 + 128 : kW) : q0 + 64;
  int kn = k_end - k_start;  // 64 or 128
  int kfr = kn >> 4;         // 4 or 8
  const u16* Q = Qbf + ((size_t)dir * 192 + nh) * kW * 64;
  const u16* K = Kbf + ((size_t)dir * 192 + nh) * kW * 64;
  const u16* V = Vbf + ((size_t)dir * 192 + nh) * 96 * kW;
  float* Aout = Abase + (size_t)dir * 50331648 + (size_t)nh * kW * kW;
  u16* Obase = Obf + (size_t)dir * 9437184;

  __shared__ __attribute__((aligned(16))) u16 smem[26880];
  u16* Qs = smem;           // [64][72]
  u16* Ks = smem + 4608;    // [128][72]
  u16* Ps = smem;           // [64][136]  (aliases Qs/Ks after barrier)
  u16* Vt = smem + 13824;   // [96][136]

  int tid = threadIdx.x;
  int wid = tid >> 6, lane = tid & 63;
  int lr = lane & 15, g = lane >> 4;

  for (int u = tid; u < 64 * 16; u += 256) {
    int row = u >> 4, c4 = (u & 15) * 4;
    *reinterpret_cast<us4*>(&Qs[row * 72 + c4]) =
        *reinterpret_cast<const us4*>(&Q[(size_t)(q0 + row) * 64 + c4]);
  }
  for (int u = tid; u < 128 * 16; u += 256) {  // rows >= kn are garbage, masked later
    int row = u >> 4, c4 = (u & 15) * 4;
    *reinterpret_cast<us4*>(&Ks[row * 72 + c4]) =
        *reinterpret_cast<const us4*>(&K[(size_t)(k_start + row) * 64 + c4]);
  }
  for (int u = tid; u < 96 * 32; u += 256) {
    int row = u >> 5, c4 = (u & 31) * 4;
    *reinterpret_cast<us4*>(&Vt[row * 136 + c4]) =
        *reinterpret_cast<const us4*>(&V[(size_t)row * kW + k_start + c4]);
  }
  __syncthreads();

  // QK^T (transposed): sT[kf] covers k-rows kf*16..+15, q-col = wid*16+lr
  f32x4 sT[8];
#pragma unroll
  for (int kf = 0; kf < 8; ++kf) sT[kf] = f32x4{0.f, 0.f, 0.f, 0.f};
#pragma unroll
  for (int kc = 0; kc < 2; ++kc) {
    bf16x8 bq = *reinterpret_cast<const bf16x8*>(&Qs[(wid * 16 + lr) * 72 + kc * 32 + g * 8]);
#pragma unroll
    for (int kf = 0; kf < 8; ++kf) {
      bf16x8 ak = *reinterpret_cast<const bf16x8*>(&Ks[(kf * 16 + lr) * 72 + kc * 32 + g * 8]);
      sT[kf] = __builtin_amdgcn_mfma_f32_16x16x32_bf16(ak, bq, sT[kf], 0, 0, 0);
    }
  }

  // mask + softmax (per lane: q fixed, 32 k-values; reduce over g via xor 16/32)
  int i = q0 + wid * 16 + lr;
  float mx = -INFINITY;
#pragma unroll
  for (int kf = 0; kf < 8; ++kf) {
#pragma unroll
    for (int r = 0; r < 4; ++r) {
      int jj = k_start + kf * 16 + g * 4 + r;
      bool valid = (jj < k_end) &&
                   (dir == 0 ? (jj >= i && jj - i <= 64) : (jj <= i && i - jj <= 64));
      float v = valid ? sT[kf][r] * 0.125f : -INFINITY;
      sT[kf][r] = v;
      mx = fmaxf(mx, v);
    }
  }
  mx = fmaxf(mx, __shfl_xor(mx, 16));
  mx = fmaxf(mx, __shfl_xor(mx, 32));
  float ssum = 0.f;
#pragma unroll
  for (int kf = 0; kf < 8; ++kf) {
#pragma unroll
    for (int r = 0; r < 4; ++r) {
      float e = __expf(sT[kf][r] - mx);
      sT[kf][r] = e;
      ssum += e;
    }
  }
  ssum += __shfl_xor(ssum, 16);
  ssum += __shfl_xor(ssum, 32);
  float inv = 1.f / ssum;

  __syncthreads();  // all Qs/Ks reads done; smem becomes Ps

  {
    float* arow = Aout + (size_t)i * kW + k_start;
#pragma unroll
    for (int kf = 0; kf < 8; ++kf) {
      float4 pv;
      us4 pb;
#pragma unroll
      for (int r = 0; r < 4; ++r) {
        float p = sT[kf][r] * inv;
        p = (p > 0.01f) ? p : 0.f;
        (&pv.x)[r] = p;
        pb[r] = f2bf(p);
      }
      *reinterpret_cast<us4*>(&Ps[(wid * 16 + lr) * 136 + kf * 16 + g * 4]) = pb;
      if (kf < kfr)
        *reinterpret_cast<float4*>(arow + kf * 16 + g * 4) = pv;
    }
  }
  // zero-fill A outside the band (full 512-wide rows; replaces memset)
  {
    int row = tid >> 2, t4 = tid & 3;
    float4 z4 = make_float4(0.f, 0.f, 0.f, 0.f);
    float* arow = Aout + (size_t)(q0 + row) * kW;
    for (int c4 = t4; c4 < (k_start >> 2); c4 += 4)
      *reinterpret_cast<float4*>(arow + c4 * 4) = z4;
    for (int c4 = (k_end >> 2) + t4; c4 < 128; c4 += 4)
      *reinterpret_cast<float4*>(arow + c4 * 4) = z4;
  }
  __syncthreads();

  // PV: O[64q][96e] = P @ V ; wave wid owns q-frag wid
  f32x4 oacc[6];
#pragma unroll
  for (int ef = 0; ef < 6; ++ef) oacc[ef] = f32x4{0.f, 0.f, 0.f, 0.f};
#pragma unroll
  for (int kc = 0; kc < 4; ++kc) {
    bf16x8 ap = *reinterpret_cast<const bf16x8*>(&Ps[(wid * 16 + lr) * 136 + kc * 32 + g * 8]);
#pragma unroll
    for (int ef = 0; ef < 6; ++ef) {
      bf16x8 bv = *reinterpret_cast<const bf16x8*>(&Vt[(ef * 16 + lr) * 136 + kc * 32 + g * 8]);
      oacc[ef] = __builtin_amdgcn_mfma_f32_16x16x32_bf16(ap, bv, oacc[ef], 0, 0, 0);
    }
  }
  int n_ = nh >> 1, h_ = nh & 1;
#pragma unroll
  for (int ef = 0; ef < 6; ++ef) {
    int e = ef * 16 + lr;
#pragma unroll
    for (int r = 0; r < 4; ++r) {
      int qrow = wid * 16 + g * 4 + r;
      Obase[((size_t)n_ * kW + q0 + qrow) * kC + h_ * 96 + e] = f2bf(oacc[ef][r]);
    }
  }
}

// ---------------- out-projection (bf16 MFMA) + residual, both dirs --------------------
__global__ void __launch_bounds__(256) proj_mfma(
    const float* __restrict__ wo0, const float* __restrict__ wo1,
    const float* __restrict__ bo0, const float* __restrict__ bo1,
    const u16* __restrict__ Obf, const u16* __restrict__ lraw,
    const u16* __restrict__ rraw, float* __restrict__ lofb,
    u16* __restrict__ lobfb) {
  int l0 = blockIdx.x * 64;
  int o0 = blockIdx.y * 64;
  int z = blockIdx.z;
  int dir = z / 96, n = z % 96;
  const float* wo = dir ? wo1 : wo0;
  const float* bias = dir ? bo1 : bo0;
  const u16* Osrc = Obf + (size_t)dir * 9437184;
  const u16* resbf = dir ? rraw : lraw;
  float* lof = lofb + (size_t)dir * 9437184;
  u16* lobf = lobfb + (size_t)dir * 9437184;
  __shared__ __attribute__((aligned(16))) u16 As[64][72];
  __shared__ __attribute__((aligned(16))) u16 Bs[64][72];
  int tid = threadIdx.x;
  int wid = tid >> 6, lane = tid & 63;
  int wm = wid >> 1, wn = wid & 1;
  int lr = lane & 15, lk = (lane >> 4) * 8;
  f32x4 acc[2][2] = {};
  for (int c0 = 0; c0 < kC; c0 += 64) {
    for (int u = tid; u < 64 * 16; u += 256) {
      int row = u >> 4, q = u & 15;
      *reinterpret_cast<us4*>(&As[row][q * 4]) = *reinterpret_cast<const us4*>(
          &Osrc[((size_t)n * kW + l0 + row) * kC + c0 + q * 4]);
    }
    for (int u = tid; u < 64 * 16; u += 256) {
      int o = u >> 4, q = u & 15;
      float4 v = *reinterpret_cast<const float4*>(wo + (size_t)(o0 + o) * kC + c0 + q * 4);
      us4 h = {f2bf(v.x), f2bf(v.y), f2bf(v.z), f2bf(v.w)};
      *reinterpret_cast<us4*>(&Bs[o][q * 4]) = h;
    }
    __syncthreads();
#pragma unroll
    for (int ks = 0; ks < 2; ++ks) {
      bf16x8 a[2], b[2];
#pragma unroll
      for (int m2 = 0; m2 < 2; ++m2)
        a[m2] = *reinterpret_cast<const bf16x8*>(&As[wm * 32 + m2 * 16 + lr][ks * 32 + lk]);
#pragma unroll
      for (int n2 = 0; n2 < 2; ++n2)
        b[n2] = *reinterpret_cast<const bf16x8*>(&Bs[wn * 32 + n2 * 16 + lr][ks * 32 + lk]);
#pragma unroll
      for (int m2 = 0; m2 < 2; ++m2)
#pragma unroll
        for (int n2 = 0; n2 < 2; ++n2)
          acc[m2][n2] = __builtin_amdgcn_mfma_f32_16x16x32_bf16(a[m2], b[n2], acc[m2][n2], 0, 0, 0);
    }
    __syncthreads();
  }
  int lg = lane >> 4;
#pragma unroll
  for (int n2 = 0; n2 < 2; ++n2) {
    int o = o0 + wn * 32 + n2 * 16 + lr;
    float bsv = bias[o];
#pragma unroll
    for (int m2 = 0; m2 < 2; ++m2) {
#pragma unroll
      for (int rg = 0; rg < 4; ++rg) {
        int l = l0 + wm * 32 + m2 * 16 + lg * 4 + rg;
        size_t idx = ((size_t)n * kW + l) * kC + o;
        float v = acc[m2][n2][rg] + bsv + bf2f(resbf[idx]);
        lof[idx] = v;
        lobf[idx] = f2bf(v);
      }
    }
  }
}

// ---------------- FF (bf16 MFMA) + residual + transpose out, both dirs ----------------
__global__ void __launch_bounds__(256) ff_mfma(
    const float* __restrict__ fw0, const float* __restrict__ fw1,
    const float* __restrict__ fb0, const float* __restrict__ fb1,
    const u16* __restrict__ lobfb, const float* __restrict__ lofb,
    float* __restrict__ outbase) {
  int l0 = blockIdx.x * 64;
  int o0 = blockIdx.y * 64;
  int z = blockIdx.z;
  int dir = z / 96, n = z % 96;
  const float* fw = dir ? fw1 : fw0;
  const float* bias = dir ? fb1 : fb0;
  const u16* lobf = lobfb + (size_t)dir * 9437184;
  const float* lof = lofb + (size_t)dir * 9437184;
  float* outb = outbase + (size_t)dir * 9437184;
  int bb = n / kHH, h = n % kHH;
  __shared__ __attribute__((aligned(16))) u16 As[64][72];
  __shared__ __attribute__((aligned(16))) u16 Bs[64][72];
  int tid = threadIdx.x;
  int wid = tid >> 6, lane = tid & 63;
  int wm = wid >> 1, wn = wid & 1;
  int lr = lane & 15, lk = (lane >> 4) * 8;
  f32x4 acc[2][2] = {};
  for (int c0 = 0; c0 < kC; c0 += 64) {
    for (int u = tid; u < 64 * 16; u += 256) {
      int row = u >> 4, q = u & 15;
      *reinterpret_cast<us4*>(&As[row][q * 4]) = *reinterpret_cast<const us4*>(
          &lobf[((size_t)n * kW + l0 + row) * kC + c0 + q * 4]);
    }
    for (int u = tid; u < 64 * 16; u += 256) {
      int o = u >> 4, q = u & 15;
      float4 v = *reinterpret_cast<const float4*>(fw + (size_t)(o0 + o) * kC + c0 + q * 4);
      us4 h = {f2bf(v.x), f2bf(v.y), f2bf(v.z), f2bf(v.w)};
      *reinterpret_cast<us4*>(&Bs[o][q * 4]) = h;
    }
    __syncthreads();
#pragma unroll
    for (int ks = 0; ks < 2; ++ks) {
      bf16x8 a[2], b[2];
#pragma unroll
      for (int m2 = 0; m2 < 2; ++m2)
        a[m2] = *reinterpret_cast<const bf16x8*>(&As[wm * 32 + m2 * 16 + lr][ks * 32 + lk]);
#pragma unroll
      for (int n2 = 0; n2 < 2; ++n2)
        b[n2] = *reinterpret_cast<const bf16x8*>(&Bs[wn * 32 + n2 * 16 + lr][ks * 32 + lk]);
#pragma unroll
      for (int m2 = 0; m2 < 2; ++m2)
#pragma unroll
        for (int n2 = 0; n2 < 2; ++n2)
          acc[m2][n2] = __builtin_amdgcn_mfma_f32_16x16x32_bf16(a[m2], b[n2], acc[m2][n2], 0, 0, 0);
    }
    __syncthreads();
  }
  int lg = lane >> 4;
#pragma unroll
  for (int n2 = 0; n2 < 2; ++n2) {
    int o = o0 + wn * 32 + n2 * 16 + lr;
    float bsv = bias[o];
#pragma unroll
    for (int m2 = 0; m2 < 2; ++m2) {
#pragma unroll
      for (int rg = 0; rg < 4; ++rg) {
        int l = l0 + wm * 32 + m2 * 16 + lg * 4 + rg;
        float res = lof[((size_t)n * kW + l) * kC + o];
        outb[(((size_t)bb * kC + o) * kHH + h) * kW + l] = acc[m2][n2][rg] + bsv + res;
      }
    }
  }
}

extern "C" void kernel_launch(void* const* d_in, const int* in_sizes, int n_in,
                              void* d_out, int out_size, void* d_ws, size_t ws_size,
                              hipStream_t stream) {
  const float* l = (const float*)d_in[0];
  const float* r = (const float*)d_in[1];
  float* out = (float*)d_out;
  float* ws = (float*)d_ws;

  // workspace layout (float-element offsets)
  u16* lnl_bf  = (u16*)(ws + 0);          // [96][512][192] bf16
  u16* lnr_bf  = (u16*)(ws + 4718592);
  u16* lraw_bf = (u16*)(ws + 9437184);
  u16* rraw_bf = (u16*)(ws + 14155776);
  u16* wall    = (u16*)(ws + 18874368);   // 516096 u16
  float* ball  = ws + 19136512;           // 896 f
  u16* Qbf     = (u16*)(ws + 19137536);   // [2][192][512][64] bf16
  u16* Kbf     = (u16*)(ws + 25428992);
  u16* Vbf     = (u16*)(ws + 31720448);   // [2][192][96][512] bf16
  u16* Obf     = (u16*)(ws + 41157632);   // [2][96][512][192] bf16
  float* lof   = ws + 50594816;           // [2][96][512][192] f32
  u16* lobf    = (u16*)(ws + 69469184);   // [2][96][512][192] bf16

  ln_kernel<<<dim3(8, 96, 2), 256, 0, stream>>>(
      l, r, (const float*)d_in[2], (const float*)d_in[3],
      (const float*)d_in[4], (const float*)d_in[5],
      lnl_bf, lraw_bf, lnr_bf, rraw_bf);

  wprep_all<<<(516096 + 896 + 255) / 256, 256, 0, stream>>>(
      (const float*)d_in[6], (const float*)d_in[8], (const float*)d_in[10],
      (const float*)d_in[14], (const float*)d_in[16], (const float*)d_in[18],
      (const float*)d_in[7], (const float*)d_in[9], (const float*)d_in[11],
      (const float*)d_in[15], (const float*)d_in[17], (const float*)d_in[19],
      wall, ball);

  conv_mfma_all<<<dim3(8, 14, 96), 256, 0, stream>>>(
      lnl_bf, lnr_bf, lraw_bf, rraw_bf, wall, ball, Qbf, Kbf, Vbf);

  attn_mfma<<<dim3(8, 192, 2), 256, 0, stream>>>(
      Qbf, Kbf, Vbf, out + (size_t)18874368, Obf);

  proj_mfma<<<dim3(8, 3, 192), 256, 0, stream>>>(
      (const float*)d_in[12], (const float*)d_in[20],
      (const float*)d_in[13], (const float*)d_in[21],
      Obf, lraw_bf, rraw_bf, lof, lobf);

  ff_mfma<<<dim3(8, 3, 192), 256, 0, stream>>>(
      (const float*)d_in[22], (const float*)d_in[24],
      (const float*)d_in[23], (const float*)d_in[25],
      lobf, lof, out);
}

// Round 4
// 487.493 us; speedup vs baseline: 3.4499x; 1.1942x over previous
//
#include <hip/hip_runtime.h>
#include <cstddef>
#include <cstdint>

constexpr int kC = 192;    // channels
constexpr int kW = 512;    // sequence length
constexpr int kHH = 48;    // H

typedef unsigned short u16;
typedef __attribute__((ext_vector_type(8))) short bf16x8;
typedef __attribute__((ext_vector_type(4))) float f32x4;
typedef __attribute__((ext_vector_type(4))) unsigned short us4;

__device__ inline u16 f2bf(float f) {
  union { float f; uint32_t u; } v; v.f = f;
  uint32_t r = v.u + 0x7FFF + ((v.u >> 16) & 1);  // RNE
  return (u16)(r >> 16);
}
__device__ inline float bf2f(u16 u) {
  return __uint_as_float(((uint32_t)u) << 16);
}

// ---------------- LayerNorm (both tensors, merged) ------------------------------------
__global__ void __launch_bounds__(256) ln_kernel(
    const float* __restrict__ xl, const float* __restrict__ xr,
    const float* __restrict__ gl, const float* __restrict__ bl,
    const float* __restrict__ gr, const float* __restrict__ br,
    u16* __restrict__ lnl, u16* __restrict__ lraw,
    u16* __restrict__ lnr, u16* __restrict__ rraw) {
  int n = blockIdx.y;
  int w0 = blockIdx.x * 64;
  int side = blockIdx.z;
  const float* x = side ? xr : xl;
  const float* g = side ? gr : gl;
  const float* b = side ? br : bl;
  u16* lnout = side ? lnr : lnl;
  u16* rawout = side ? rraw : lraw;
  int bb = n / kHH, h = n % kHH;
  __shared__ float tile[64][193];
  __shared__ float red[8][64];
  __shared__ float mean_s[64], rstd_s[64];
  int tid = threadIdx.x;
  int lane = tid & 63, wv = tid >> 6;
  for (int c = wv; c < kC; c += 4)
    tile[lane][c] = x[(((size_t)bb * kC + c) * kHH + h) * kW + w0 + lane];
  __syncthreads();
  {
    int w = tid & 63, part = tid >> 6;
    float s = 0.f, s2 = 0.f;
    const float* row = &tile[w][0];
    for (int c = part * 48; c < part * 48 + 48; ++c) {
      float v = row[c];
      s += v; s2 += v * v;
    }
    red[part][w] = s;
    red[part + 4][w] = s2;
  }
  __syncthreads();
  if (tid < 64) {
    float s = red[0][tid] + red[1][tid] + red[2][tid] + red[3][tid];
    float s2 = red[4][tid] + red[5][tid] + red[6][tid] + red[7][tid];
    float m = s * (1.f / 192.f);
    float var = s2 * (1.f / 192.f) - m * m;
    mean_s[tid] = m;
    rstd_s[tid] = rsqrtf(var + 1e-5f);
  }
  __syncthreads();
  for (int u = tid; u < 64 * 48; u += 256) {
    int w = u / 48, c4 = (u % 48) * 4;
    float mm = mean_s[w], rs = rstd_s[w];
    us4 lp, rp;
#pragma unroll
    for (int j = 0; j < 4; ++j) {
      float raw = tile[w][c4 + j];
      rp[j] = f2bf(raw);
      lp[j] = f2bf((raw - mm) * rs * g[c4 + j] + b[c4 + j]);
    }
    size_t idx = ((size_t)n * kW + w0 + w) * kC + c4;
    *reinterpret_cast<us4*>(&lnout[idx]) = lp;
    *reinterpret_cast<us4*>(&rawout[idx]) = rp;
  }
}

// ---------------- weight prep (all 6 convs + biases) ----------------------------------
__global__ void wprep_all(
    const float* wq0, const float* wk0, const float* wv0,
    const float* wq1, const float* wk1, const float* wv1,
    const float* bq0, const float* bk0, const float* bv0,
    const float* bq1, const float* bk1, const float* bv1,
    u16* __restrict__ wall, float* __restrict__ ball) {
  int idx = blockIdx.x * 256 + threadIdx.x;
  if (idx < 516096) {
    int dir = idx / 258048, off = idx % 258048;
    const float* src; int soff;
    if (off < 73728) { src = dir ? wq1 : wq0; soff = off; }
    else if (off < 147456) { src = dir ? wk1 : wk0; soff = off - 73728; }
    else { src = dir ? wv1 : wv0; soff = off - 147456; }
    int o = soff / 576, k = soff % 576, t = k / 192, c = k % 192;
    wall[idx] = f2bf(src[((size_t)o * kC + c) * 3 + t]);
  } else if (idx < 516096 + 896) {
    int bi = idx - 516096;
    int dir = bi / 448, boff = bi % 448;
    const float* s; int so;
    if (boff < 128) { s = dir ? bq1 : bq0; so = boff; }
    else if (boff < 256) { s = dir ? bk1 : bk0; so = boff - 128; }
    else { s = dir ? bv1 : bv0; so = boff - 256; }
    ball[bi] = s[so];
  }
}

// ---------------- conv1d(k=3) bf16 MFMA: one block = 64l x full Cout ------------------
// A staged once (66 rows x 192c), B streamed per (tap, c0) chunk.
template <int NF>  // n-frags per wave; Cout = NF*32
__device__ __forceinline__ void conv_accum(
    const u16* __restrict__ in, const u16* __restrict__ w2,
    int n, int l0, u16* As, u16* Bs, f32x4 (&acc)[2][6]) {
  int tid = threadIdx.x;
  int wid = tid >> 6, lane = tid & 63;
  int wm = wid >> 1, wn = wid & 1;
  int lr = lane & 15, g = lane >> 4;
  // stage A once: rows l0-1 .. l0+64 (66 rows), all 192 channels, stride 200
  for (int u = tid; u < 66 * 48; u += 256) {
    int row = u / 48, q = u % 48;
    int l = l0 - 1 + row;
    us4 v = {0, 0, 0, 0};
    if (l >= 0 && l < kW)
      v = *reinterpret_cast<const us4*>(in + ((size_t)n * kW + l) * kC + q * 4);
    *reinterpret_cast<us4*>(&As[row * 200 + q * 4]) = v;
  }
#pragma unroll
  for (int t = 0; t < 3; ++t) {
#pragma unroll
    for (int c0 = 0; c0 < 192; c0 += 64) {
      __syncthreads();  // first iter: A done; later: Bs readers done
      for (int u = tid; u < NF * 32 * 16; u += 256) {
        int o = u >> 4, q = u & 15;
        *reinterpret_cast<us4*>(&Bs[o * 72 + q * 4]) =
            *reinterpret_cast<const us4*>(w2 + (size_t)o * 576 + t * 192 + c0 + q * 4);
      }
      __syncthreads();
#pragma unroll
      for (int ks = 0; ks < 2; ++ks) {
        bf16x8 a[2], b[NF];
#pragma unroll
        for (int m2 = 0; m2 < 2; ++m2)
          a[m2] = *reinterpret_cast<const bf16x8*>(
              &As[(wm * 32 + m2 * 16 + lr + t) * 200 + c0 + ks * 32 + g * 8]);
#pragma unroll
        for (int nf = 0; nf < NF; ++nf)
          b[nf] = *reinterpret_cast<const bf16x8*>(
              &Bs[(wn * NF * 16 + nf * 16 + lr) * 72 + ks * 32 + g * 8]);
#pragma unroll
        for (int m2 = 0; m2 < 2; ++m2)
#pragma unroll
          for (int nf = 0; nf < NF; ++nf)
            acc[m2][nf] = __builtin_amdgcn_mfma_f32_16x16x32_bf16(a[m2], b[nf], acc[m2][nf], 0, 0, 0);
      }
    }
  }
}

__global__ void __launch_bounds__(256) conv_mfma_all(
    const u16* __restrict__ lnl, const u16* __restrict__ lnr,
    const u16* __restrict__ lraw, const u16* __restrict__ rraw,
    const u16* __restrict__ wall, const float* __restrict__ ball,
    u16* __restrict__ Qbf, u16* __restrict__ Kbf, u16* __restrict__ Vbf) {
  int l0 = blockIdx.x * 64;
  int jid = blockIdx.y;
  int n = blockIdx.z;
  int dir = jid / 3, which = jid % 3;
  const u16* in = which == 0 ? (dir ? lnr : lnl)
                : which == 1 ? (dir ? lnl : lnr)
                             : (dir ? lraw : rraw);
  const u16* w2 = wall + (size_t)dir * 258048 +
                  (which == 0 ? 0 : which == 1 ? 73728 : 147456);
  const float* bias = ball + dir * 448 + (which == 0 ? 0 : which == 1 ? 128 : 256);

  __shared__ __attribute__((aligned(16))) u16 As[66 * 200];
  __shared__ __attribute__((aligned(16))) u16 Bs[192 * 72];
  int tid = threadIdx.x;
  int wid = tid >> 6, lane = tid & 63;
  int wm = wid >> 1, wn = wid & 1;
  int lr = lane & 15, g = lane >> 4;
  f32x4 acc[2][6] = {};
  if (which < 2) {
    conv_accum<4>(in, w2, n, l0, As, Bs, acc);
    u16* outp = (which == 0 ? Qbf : Kbf) + (size_t)dir * 6291456;
#pragma unroll
    for (int nf = 0; nf < 4; ++nf) {
      int o = wn * 64 + nf * 16 + lr;
      int hh = o >> 6, e = o & 63;
      float bsv = bias[o];
#pragma unroll
      for (int m2 = 0; m2 < 2; ++m2) {
#pragma unroll
        for (int rg = 0; rg < 4; ++rg) {
          int l = l0 + wm * 32 + m2 * 16 + g * 4 + rg;
          outp[((size_t)(n * 2 + hh) * kW + l) * 64 + e] = f2bf(acc[m2][nf][rg] + bsv);
        }
      }
    }
  } else {
    conv_accum<6>(in, w2, n, l0, As, Bs, acc);
    u16* outp = Vbf + (size_t)dir * 9437184;
#pragma unroll
    for (int nf = 0; nf < 6; ++nf) {
      int o = wn * 96 + nf * 16 + lr;
      int hh = wn, e = nf * 16 + lr;
      float bsv = bias[o];
#pragma unroll
      for (int m2 = 0; m2 < 2; ++m2) {
        int lb = l0 + wm * 32 + m2 * 16 + g * 4;
        us4 p;
#pragma unroll
        for (int rg = 0; rg < 4; ++rg) p[rg] = f2bf(acc[m2][nf][rg] + bsv);
        *reinterpret_cast<us4*>(&outp[((size_t)(n * 2 + hh) * 96 + e) * kW + lb]) = p;
      }
    }
  }
}

// ---------------- banded attention, bf16 MFMA, both dirs ------------------------------
__global__ void __launch_bounds__(256) attn_mfma(
    const u16* __restrict__ Qbf, const u16* __restrict__ Kbf,
    const u16* __restrict__ Vbf, float* __restrict__ Abase,
    u16* __restrict__ Obf) {
  int qb = blockIdx.x;
  int nh = blockIdx.y;
  int dir = blockIdx.z;
  int q0 = qb * 64;
  int k_start = dir == 0 ? q0 : (q0 >= 64 ? q0 - 64 : 0);
  int k_end = dir == 0 ? (q0 + 128 <= kW ? q0 + 128 : kW) : q0 + 64;
  int kfr = (k_end - k_start) >> 4;  // 4 or 8
  const u16* Q = Qbf + ((size_t)dir * 192 + nh) * kW * 64;
  const u16* K = Kbf + ((size_t)dir * 192 + nh) * kW * 64;
  const u16* V = Vbf + ((size_t)dir * 192 + nh) * 96 * kW;
  float* Aout = Abase + (size_t)dir * 50331648 + (size_t)nh * kW * kW;
  u16* Obase = Obf + (size_t)dir * 9437184;

  __shared__ __attribute__((aligned(16))) u16 smem[26880];
  u16* Qs = smem;           // [64][72]
  u16* Ks = smem + 4608;    // [128][72]
  u16* Ps = smem;           // [64][136] (aliases after barrier)
  u16* Vt = smem + 13824;   // [96][136]

  int tid = threadIdx.x;
  int wid = tid >> 6, lane = tid & 63;
  int lr = lane & 15, g = lane >> 4;

  for (int u = tid; u < 64 * 16; u += 256) {
    int row = u >> 4, c4 = (u & 15) * 4;
    *reinterpret_cast<us4*>(&Qs[row * 72 + c4]) =
        *reinterpret_cast<const us4*>(&Q[(size_t)(q0 + row) * 64 + c4]);
  }
  for (int u = tid; u < 128 * 16; u += 256) {
    int row = u >> 4, c4 = (u & 15) * 4;
    *reinterpret_cast<us4*>(&Ks[row * 72 + c4]) =
        *reinterpret_cast<const us4*>(&K[(size_t)(k_start + row) * 64 + c4]);
  }
  for (int u = tid; u < 96 * 32; u += 256) {
    int row = u >> 5, c4 = (u & 31) * 4;
    *reinterpret_cast<us4*>(&Vt[row * 136 + c4]) =
        *reinterpret_cast<const us4*>(&V[(size_t)row * kW + k_start + c4]);
  }
  __syncthreads();

  f32x4 sT[8];
#pragma unroll
  for (int kf = 0; kf < 8; ++kf) sT[kf] = f32x4{0.f, 0.f, 0.f, 0.f};
#pragma unroll
  for (int kc = 0; kc < 2; ++kc) {
    bf16x8 bq = *reinterpret_cast<const bf16x8*>(&Qs[(wid * 16 + lr) * 72 + kc * 32 + g * 8]);
#pragma unroll
    for (int kf = 0; kf < 8; ++kf) {
      bf16x8 ak = *reinterpret_cast<const bf16x8*>(&Ks[(kf * 16 + lr) * 72 + kc * 32 + g * 8]);
      sT[kf] = __builtin_amdgcn_mfma_f32_16x16x32_bf16(ak, bq, sT[kf], 0, 0, 0);
    }
  }

  int i = q0 + wid * 16 + lr;
  float mx = -INFINITY;
#pragma unroll
  for (int kf = 0; kf < 8; ++kf) {
#pragma unroll
    for (int r = 0; r < 4; ++r) {
      int jj = k_start + kf * 16 + g * 4 + r;
      bool valid = (jj < k_end) &&
                   (dir == 0 ? (jj >= i && jj - i <= 64) : (jj <= i && i - jj <= 64));
      float v = valid ? sT[kf][r] * 0.125f : -INFINITY;
      sT[kf][r] = v;
      mx = fmaxf(mx, v);
    }
  }
  mx = fmaxf(mx, __shfl_xor(mx, 16));
  mx = fmaxf(mx, __shfl_xor(mx, 32));
  float ssum = 0.f;
#pragma unroll
  for (int kf = 0; kf < 8; ++kf) {
#pragma unroll
    for (int r = 0; r < 4; ++r) {
      float e = __expf(sT[kf][r] - mx);
      sT[kf][r] = e;
      ssum += e;
    }
  }
  ssum += __shfl_xor(ssum, 16);
  ssum += __shfl_xor(ssum, 32);
  float inv = 1.f / ssum;

  __syncthreads();  // Qs/Ks reads done; smem becomes Ps

  {
    float* arow = Aout + (size_t)i * kW + k_start;
#pragma unroll
    for (int kf = 0; kf < 8; ++kf) {
      f32x4 pv;
      us4 pb;
#pragma unroll
      for (int r = 0; r < 4; ++r) {
        float p = sT[kf][r] * inv;
        p = (p > 0.01f) ? p : 0.f;
        pv[r] = p;
        pb[r] = f2bf(p);
      }
      *reinterpret_cast<us4*>(&Ps[(wid * 16 + lr) * 136 + kf * 16 + g * 4]) = pb;
      if (kf < kfr)
        __builtin_nontemporal_store(pv, reinterpret_cast<f32x4*>(arow + kf * 16 + g * 4));
    }
  }
  // zero-fill A outside the band
  {
    int row = tid >> 2, t4 = tid & 3;
    f32x4 z4 = {0.f, 0.f, 0.f, 0.f};
    float* arow = Aout + (size_t)(q0 + row) * kW;
    for (int c4 = t4; c4 < (k_start >> 2); c4 += 4)
      __builtin_nontemporal_store(z4, reinterpret_cast<f32x4*>(arow + c4 * 4));
    for (int c4 = (k_end >> 2) + t4; c4 < 128; c4 += 4)
      __builtin_nontemporal_store(z4, reinterpret_cast<f32x4*>(arow + c4 * 4));
  }
  __syncthreads();

  // PV
  f32x4 oacc[6];
#pragma unroll
  for (int ef = 0; ef < 6; ++ef) oacc[ef] = f32x4{0.f, 0.f, 0.f, 0.f};
#pragma unroll
  for (int kc = 0; kc < 4; ++kc) {
    bf16x8 ap = *reinterpret_cast<const bf16x8*>(&Ps[(wid * 16 + lr) * 136 + kc * 32 + g * 8]);
#pragma unroll
    for (int ef = 0; ef < 6; ++ef) {
      bf16x8 bv = *reinterpret_cast<const bf16x8*>(&Vt[(ef * 16 + lr) * 136 + kc * 32 + g * 8]);
      oacc[ef] = __builtin_amdgcn_mfma_f32_16x16x32_bf16(ap, bv, oacc[ef], 0, 0, 0);
    }
  }
  // transpose O through LDS for coalesced global write
  __syncthreads();
  u16* Os2 = smem;  // [64][104]
#pragma unroll
  for (int ef = 0; ef < 6; ++ef) {
    int e = ef * 16 + lr;
#pragma unroll
    for (int r = 0; r < 4; ++r)
      Os2[(wid * 16 + g * 4 + r) * 104 + e] = f2bf(oacc[ef][r]);
  }
  __syncthreads();
  int n_ = nh >> 1, h_ = nh & 1;
  for (int u = tid; u < 64 * 24; u += 256) {
    int q = u / 24, c4 = (u % 24) * 4;
    *reinterpret_cast<us4*>(&Obase[((size_t)n_ * kW + q0 + q) * kC + h_ * 96 + c4]) =
        *reinterpret_cast<const us4*>(&Os2[q * 104 + c4]);
  }
}

// ---------------- fused out-projection + FF + residuals + transpose-out ---------------
__global__ void __launch_bounds__(256) projff_mfma(
    const float* __restrict__ wo0, const float* __restrict__ wo1,
    const float* __restrict__ bo0, const float* __restrict__ bo1,
    const float* __restrict__ fw0, const float* __restrict__ fw1,
    const float* __restrict__ fb0, const float* __restrict__ fb1,
    const u16* __restrict__ Obf, const u16* __restrict__ lraw,
    const u16* __restrict__ rraw, float* __restrict__ outbase) {
  int l0 = blockIdx.x * 64;
  int z = blockIdx.y;
  int dir = z / 96, n = z % 96;
  const float* wo = dir ? wo1 : wo0;
  const float* bo_ = dir ? bo1 : bo0;
  const float* fw = dir ? fw1 : fw0;
  const float* fb_ = dir ? fb1 : fb0;
  const u16* Osrc = Obf + (size_t)dir * 9437184;
  const u16* resbf = dir ? rraw : lraw;
  float* outb = outbase + (size_t)dir * 9437184;
  int bb = n / kHH, h = n % kHH;

  __shared__ __attribute__((aligned(16))) u16 Xs[64 * 200];  // O tile, then lo_bf
  __shared__ __attribute__((aligned(16))) u16 Rs[64 * 200];  // residual tile
  __shared__ __attribute__((aligned(16))) u16 Bs[192 * 72];

  int tid = threadIdx.x;
  int wid = tid >> 6, lane = tid & 63;
  int wm = wid >> 1, wn = wid & 1;
  int lr = lane & 15, g = lane >> 4;

  for (int u = tid; u < 64 * 48; u += 256) {
    int row = u / 48, q = u % 48;
    size_t src = ((size_t)n * kW + l0 + row) * kC + q * 4;
    *reinterpret_cast<us4*>(&Xs[row * 200 + q * 4]) =
        *reinterpret_cast<const us4*>(&Osrc[src]);
    *reinterpret_cast<us4*>(&Rs[row * 200 + q * 4]) =
        *reinterpret_cast<const us4*>(&resbf[src]);
  }

  // ---- proj phase ----
  f32x4 accp[2][6] = {};
#pragma unroll
  for (int c0 = 0; c0 < 192; c0 += 64) {
    __syncthreads();
    for (int u = tid; u < 192 * 16; u += 256) {
      int o = u >> 4, q = u & 15;
      float4 v = *reinterpret_cast<const float4*>(wo + (size_t)o * kC + c0 + q * 4);
      us4 hb = {f2bf(v.x), f2bf(v.y), f2bf(v.z), f2bf(v.w)};
      *reinterpret_cast<us4*>(&Bs[o * 72 + q * 4]) = hb;
    }
    __syncthreads();
#pragma unroll
    for (int ks = 0; ks < 2; ++ks) {
      bf16x8 a[2], b[6];
#pragma unroll
      for (int m2 = 0; m2 < 2; ++m2)
        a[m2] = *reinterpret_cast<const bf16x8*>(
            &Xs[(wm * 32 + m2 * 16 + lr) * 200 + c0 + ks * 32 + g * 8]);
#pragma unroll
      for (int nf = 0; nf < 6; ++nf)
        b[nf] = *reinterpret_cast<const bf16x8*>(
            &Bs[(wn * 96 + nf * 16 + lr) * 72 + ks * 32 + g * 8]);
#pragma unroll
      for (int m2 = 0; m2 < 2; ++m2)
#pragma unroll
        for (int nf = 0; nf < 6; ++nf)
          accp[m2][nf] = __builtin_amdgcn_mfma_f32_16x16x32_bf16(a[m2], b[nf], accp[m2][nf], 0, 0, 0);
    }
  }
  // epilogue: lo = proj + bo + residual; keep fp32 in regs, bf16 into Xs
  __syncthreads();  // all proj reads of Xs done
#pragma unroll
  for (int nf = 0; nf < 6; ++nf) {
    int o = wn * 96 + nf * 16 + lr;
    float bv = bo_[o];
#pragma unroll
    for (int m2 = 0; m2 < 2; ++m2) {
#pragma unroll
      for (int r = 0; r < 4; ++r) {
        int l = wm * 32 + m2 * 16 + g * 4 + r;
        float v = accp[m2][nf][r] + bv + bf2f(Rs[l * 200 + o]);
        accp[m2][nf][r] = v;
        Xs[l * 200 + o] = f2bf(v);
      }
    }
  }

  // ---- ff phase ----
  f32x4 accf[2][6] = {};
#pragma unroll
  for (int c0 = 0; c0 < 192; c0 += 64) {
    __syncthreads();  // first iter: Xs(lo_bf) writes visible; later: Bs readers done
    for (int u = tid; u < 192 * 16; u += 256) {
      int o = u >> 4, q = u & 15;
      float4 v = *reinterpret_cast<const float4*>(fw + (size_t)o * kC + c0 + q * 4);
      us4 hb = {f2bf(v.x), f2bf(v.y), f2bf(v.z), f2bf(v.w)};
      *reinterpret_cast<us4*>(&Bs[o * 72 + q * 4]) = hb;
    }
    __syncthreads();
#pragma unroll
    for (int ks = 0; ks < 2; ++ks) {
      bf16x8 a[2], b[6];
#pragma unroll
      for (int m2 = 0; m2 < 2; ++m2)
        a[m2] = *reinterpret_cast<const bf16x8*>(
            &Xs[(wm * 32 + m2 * 16 + lr) * 200 + c0 + ks * 32 + g * 8]);
#pragma unroll
      for (int nf = 0; nf < 6; ++nf)
        b[nf] = *reinterpret_cast<const bf16x8*>(
            &Bs[(wn * 96 + nf * 16 + lr) * 72 + ks * 32 + g * 8]);
#pragma unroll
      for (int m2 = 0; m2 < 2; ++m2)
#pragma unroll
        for (int nf = 0; nf < 6; ++nf)
          accf[m2][nf] = __builtin_amdgcn_mfma_f32_16x16x32_bf16(a[m2], b[nf], accf[m2][nf], 0, 0, 0);
    }
  }
  // ff epilogue: out = ff + fb + lo (regs), float4 stores, [b,c,h,w] layout
#pragma unroll
  for (int nf = 0; nf < 6; ++nf) {
    int o = wn * 96 + nf * 16 + lr;
    float bv = fb_[o];
#pragma unroll
    for (int m2 = 0; m2 < 2; ++m2) {
      f32x4 ov;
#pragma unroll
      for (int r = 0; r < 4; ++r)
        ov[r] = accf[m2][nf][r] + bv + accp[m2][nf][r];
      int l = l0 + wm * 32 + m2 * 16 + g * 4;
      *reinterpret_cast<f32x4*>(&outb[(((size_t)bb * kC + o) * kHH + h) * kW + l]) = ov;
    }
  }
}

extern "C" void kernel_launch(void* const* d_in, const int* in_sizes, int n_in,
                              void* d_out, int out_size, void* d_ws, size_t ws_size,
                              hipStream_t stream) {
  const float* l = (const float*)d_in[0];
  const float* r = (const float*)d_in[1];
  float* out = (float*)d_out;
  float* ws = (float*)d_ws;

  u16* lnl_bf  = (u16*)(ws + 0);          // [96][512][192] bf16
  u16* lnr_bf  = (u16*)(ws + 4718592);
  u16* lraw_bf = (u16*)(ws + 9437184);
  u16* rraw_bf = (u16*)(ws + 14155776);
  u16* wall    = (u16*)(ws + 18874368);   // 516096 u16
  float* ball  = ws + 19136512;           // 896 f
  u16* Qbf     = (u16*)(ws + 19137536);   // [2][192][512][64] bf16
  u16* Kbf     = (u16*)(ws + 25428992);
  u16* Vbf     = (u16*)(ws + 31720448);   // [2][192][96][512] bf16
  u16* Obf     = (u16*)(ws + 41157632);   // [2][96][512][192] bf16

  ln_kernel<<<dim3(8, 96, 2), 256, 0, stream>>>(
      l, r, (const float*)d_in[2], (const float*)d_in[3],
      (const float*)d_in[4], (const float*)d_in[5],
      lnl_bf, lraw_bf, lnr_bf, rraw_bf);

  wprep_all<<<(516096 + 896 + 255) / 256, 256, 0, stream>>>(
      (const float*)d_in[6], (const float*)d_in[8], (const float*)d_in[10],
      (const float*)d_in[14], (const float*)d_in[16], (const float*)d_in[18],
      (const float*)d_in[7], (const float*)d_in[9], (const float*)d_in[11],
      (const float*)d_in[15], (const float*)d_in[17], (const float*)d_in[19],
      wall, ball);

  conv_mfma_all<<<dim3(8, 6, 96), 256, 0, stream>>>(
      lnl_bf, lnr_bf, lraw_bf, rraw_bf, wall, ball, Qbf, Kbf, Vbf);

  attn_mfma<<<dim3(8, 192, 2), 256, 0, stream>>>(
      Qbf, Kbf, Vbf, out + (size_t)18874368, Obf);

  projff_mfma<<<dim3(8, 192), 256, 0, stream>>>(
      (const float*)d_in[12], (const float*)d_in[20],
      (const float*)d_in[13], (const float*)d_in[21],
      (const float*)d_in[22], (const float*)d_in[24],
      (const float*)d_in[23], (const float*)d_in[25],
      Obf, lraw_bf, rraw_bf, out);
}

// Round 5
// 397.706 us; speedup vs baseline: 4.2287x; 1.2258x over previous
//
#include <hip/hip_runtime.h>
#include <cstddef>
#include <cstdint>

constexpr int kC = 192;    // channels
constexpr int kW = 512;    // sequence length
constexpr int kHH = 48;    // H

typedef unsigned short u16;
typedef __attribute__((ext_vector_type(8))) short bf16x8;
typedef __attribute__((ext_vector_type(4))) float f32x4;
typedef __attribute__((ext_vector_type(4))) unsigned short us4;

__device__ inline u16 f2bf(float f) {
  union { float f; uint32_t u; } v; v.f = f;
  uint32_t r = v.u + 0x7FFF + ((v.u >> 16) & 1);  // RNE
  return (u16)(r >> 16);
}
__device__ inline float bf2f(u16 u) {
  return __uint_as_float(((uint32_t)u) << 16);
}

// ---------------- LayerNorm (both tensors, merged) ------------------------------------
__global__ void __launch_bounds__(256) ln_kernel(
    const float* __restrict__ xl, const float* __restrict__ xr,
    const float* __restrict__ gl, const float* __restrict__ bl,
    const float* __restrict__ gr, const float* __restrict__ br,
    u16* __restrict__ lnl, u16* __restrict__ lraw,
    u16* __restrict__ lnr, u16* __restrict__ rraw) {
  int n = blockIdx.y;
  int w0 = blockIdx.x * 64;
  int side = blockIdx.z;
  const float* x = side ? xr : xl;
  const float* g = side ? gr : gl;
  const float* b = side ? br : bl;
  u16* lnout = side ? lnr : lnl;
  u16* rawout = side ? rraw : lraw;
  int bb = n / kHH, h = n % kHH;
  __shared__ float tile[64][193];
  __shared__ float red[8][64];
  __shared__ float mean_s[64], rstd_s[64];
  int tid = threadIdx.x;
  int lane = tid & 63, wv = tid >> 6;
  for (int c = wv; c < kC; c += 4)
    tile[lane][c] = x[(((size_t)bb * kC + c) * kHH + h) * kW + w0 + lane];
  __syncthreads();
  {
    int w = tid & 63, part = tid >> 6;
    float s = 0.f, s2 = 0.f;
    const float* row = &tile[w][0];
    for (int c = part * 48; c < part * 48 + 48; ++c) {
      float v = row[c];
      s += v; s2 += v * v;
    }
    red[part][w] = s;
    red[part + 4][w] = s2;
  }
  __syncthreads();
  if (tid < 64) {
    float s = red[0][tid] + red[1][tid] + red[2][tid] + red[3][tid];
    float s2 = red[4][tid] + red[5][tid] + red[6][tid] + red[7][tid];
    float m = s * (1.f / 192.f);
    float var = s2 * (1.f / 192.f) - m * m;
    mean_s[tid] = m;
    rstd_s[tid] = rsqrtf(var + 1e-5f);
  }
  __syncthreads();
  for (int u = tid; u < 64 * 48; u += 256) {
    int w = u / 48, c4 = (u % 48) * 4;
    float mm = mean_s[w], rs = rstd_s[w];
    us4 lp, rp;
#pragma unroll
    for (int j = 0; j < 4; ++j) {
      float raw = tile[w][c4 + j];
      rp[j] = f2bf(raw);
      lp[j] = f2bf((raw - mm) * rs * g[c4 + j] + b[c4 + j]);
    }
    size_t idx = ((size_t)n * kW + w0 + w) * kC + c4;
    *reinterpret_cast<us4*>(&lnout[idx]) = lp;
    *reinterpret_cast<us4*>(&rawout[idx]) = rp;
  }
}

// ---------------- weight prep: conv weights + proj/ff weights + biases ----------------
// wall per dir: [q 128*576][k 128*576][v 192*576], layout [o][t*192+c] bf16.
// pfw: [wo0][wo1][fw0][fw1], each [192][192] bf16.
__global__ void wprep_all(
    const float* wq0, const float* wk0, const float* wv0,
    const float* wq1, const float* wk1, const float* wv1,
    const float* bq0, const float* bk0, const float* bv0,
    const float* bq1, const float* bk1, const float* bv1,
    const float* wo0, const float* wo1, const float* fw0, const float* fw1,
    u16* __restrict__ wall, u16* __restrict__ pfw, float* __restrict__ ball) {
  int idx = blockIdx.x * 256 + threadIdx.x;
  if (idx < 516096) {
    int dir = idx / 258048, off = idx % 258048;
    const float* src; int soff;
    if (off < 73728) { src = dir ? wq1 : wq0; soff = off; }
    else if (off < 147456) { src = dir ? wk1 : wk0; soff = off - 73728; }
    else { src = dir ? wv1 : wv0; soff = off - 147456; }
    int o = soff / 576, k = soff % 576, t = k / 192, c = k % 192;
    wall[idx] = f2bf(src[((size_t)o * kC + c) * 3 + t]);
  } else if (idx < 516096 + 147456) {
    int i2 = idx - 516096;
    int mat = i2 / 36864, off = i2 % 36864;
    const float* src = mat == 0 ? wo0 : mat == 1 ? wo1 : mat == 2 ? fw0 : fw1;
    pfw[i2] = f2bf(src[off]);
  } else if (idx < 516096 + 147456 + 896) {
    int bi = idx - 516096 - 147456;
    int dir = bi / 448, boff = bi % 448;
    const float* s; int so;
    if (boff < 128) { s = dir ? bq1 : bq0; so = boff; }
    else if (boff < 256) { s = dir ? bk1 : bk0; so = boff - 128; }
    else { s = dir ? bv1 : bv0; so = boff - 256; }
    ball[bi] = s[so];
  }
}

// ---------------- conv core: 128 l-rows x NF*32 Cout, B direct from L2 ----------------
template <int NF>
__device__ __forceinline__ void conv_core(
    const u16* __restrict__ in, const u16* __restrict__ w2,
    int n, int l0, u16* As, f32x4 (&acc)[4][NF]) {
  int tid = threadIdx.x;
  int wid = tid >> 6, lane = tid & 63;
  int wm = wid >> 1, wn = wid & 1;
  int lr = lane & 15, g = lane >> 4;
  // stage A once: rows l0-1 .. l0+128 (130 rows), all 192 channels, stride 200
  for (int u = tid; u < 130 * 48; u += 256) {
    int row = u / 48, q = u % 48;
    int l = l0 - 1 + row;
    us4 v = {0, 0, 0, 0};
    if (l >= 0 && l < kW)
      v = *reinterpret_cast<const us4*>(in + ((size_t)n * kW + l) * kC + q * 4);
    *reinterpret_cast<us4*>(&As[row * 200 + q * 4]) = v;
  }
  __syncthreads();
  const u16* wbase = w2 + (size_t)(wn * NF * 16 + lr) * 576 + g * 8;
#pragma unroll
  for (int t = 0; t < 3; ++t) {
#pragma unroll
    for (int c0 = 0; c0 < 192; c0 += 64) {
#pragma unroll
      for (int ks = 0; ks < 2; ++ks) {
        bf16x8 a[4], b[NF];
#pragma unroll
        for (int mf = 0; mf < 4; ++mf)
          a[mf] = *reinterpret_cast<const bf16x8*>(
              &As[(wm * 64 + mf * 16 + lr + t) * 200 + c0 + ks * 32 + g * 8]);
#pragma unroll
        for (int nf = 0; nf < NF; ++nf)
          b[nf] = *reinterpret_cast<const bf16x8*>(
              wbase + (size_t)nf * 16 * 576 + t * 192 + c0 + ks * 32);
#pragma unroll
        for (int mf = 0; mf < 4; ++mf)
#pragma unroll
          for (int nf = 0; nf < NF; ++nf)
            acc[mf][nf] = __builtin_amdgcn_mfma_f32_16x16x32_bf16(a[mf], b[nf], acc[mf][nf], 0, 0, 0);
      }
    }
  }
}

// ---------------- conv Q/K (Cout=128): out bf16 [dir][nh][512][64] --------------------
__global__ void __launch_bounds__(256) conv_qk(
    const u16* __restrict__ lnl, const u16* __restrict__ lnr,
    const u16* __restrict__ wall, const float* __restrict__ ball,
    u16* __restrict__ Qbf, u16* __restrict__ Kbf) {
  int l0 = blockIdx.x * 128;
  int jid = blockIdx.y;  // dir*2 + which(0=q,1=k)
  int n = blockIdx.z;
  int dir = jid >> 1, which = jid & 1;
  const u16* in = which == 0 ? (dir ? lnr : lnl) : (dir ? lnl : lnr);
  const u16* w2 = wall + (size_t)dir * 258048 + which * 73728;
  const float* bias = ball + dir * 448 + which * 128;

  __shared__ __attribute__((aligned(16))) u16 As[130 * 200];
  f32x4 acc[4][4] = {};
  conv_core<4>(in, w2, n, l0, As, acc);

  int tid = threadIdx.x;
  int wid = tid >> 6, lane = tid & 63;
  int wm = wid >> 1, wn = wid & 1;
  int lr = lane & 15, g = lane >> 4;
  u16* outp = (which == 0 ? Qbf : Kbf) + (size_t)dir * 6291456;
#pragma unroll
  for (int nf = 0; nf < 4; ++nf) {
    int o = wn * 64 + nf * 16 + lr;
    int hh = o >> 6, e = o & 63;
    float bsv = bias[o];
#pragma unroll
    for (int mf = 0; mf < 4; ++mf) {
#pragma unroll
      for (int rg = 0; rg < 4; ++rg) {
        int l = l0 + wm * 64 + mf * 16 + g * 4 + rg;
        outp[((size_t)(n * 2 + hh) * kW + l) * 64 + e] = f2bf(acc[mf][nf][rg] + bsv);
      }
    }
  }
}

// ---------------- conv V (Cout=192): out bf16 [dir][nh][96][512] (transposed) ---------
__global__ void __launch_bounds__(256) conv_v(
    const u16* __restrict__ lraw, const u16* __restrict__ rraw,
    const u16* __restrict__ wall, const float* __restrict__ ball,
    u16* __restrict__ Vbf) {
  int l0 = blockIdx.x * 128;
  int dir = blockIdx.y;
  int n = blockIdx.z;
  const u16* in = dir ? lraw : rraw;
  const u16* w2 = wall + (size_t)dir * 258048 + 147456;
  const float* bias = ball + dir * 448 + 256;

  __shared__ __attribute__((aligned(16))) u16 As[130 * 200];
  f32x4 acc[4][6] = {};
  conv_core<6>(in, w2, n, l0, As, acc);

  int tid = threadIdx.x;
  int wid = tid >> 6, lane = tid & 63;
  int wm = wid >> 1, wn = wid & 1;
  int lr = lane & 15, g = lane >> 4;
  u16* outp = Vbf + (size_t)dir * 9437184;
#pragma unroll
  for (int nf = 0; nf < 6; ++nf) {
    int e = nf * 16 + lr;
    float bsv = bias[wn * 96 + e];
#pragma unroll
    for (int mf = 0; mf < 4; ++mf) {
      int lb = l0 + wm * 64 + mf * 16 + g * 4;
      us4 p;
#pragma unroll
      for (int rg = 0; rg < 4; ++rg) p[rg] = f2bf(acc[mf][nf][rg] + bsv);
      *reinterpret_cast<us4*>(&outp[((size_t)(n * 2 + wn) * 96 + e) * kW + lb]) = p;
    }
  }
}

// ---------------- banded attention, bf16 MFMA, both dirs ------------------------------
__global__ void __launch_bounds__(256) attn_mfma(
    const u16* __restrict__ Qbf, const u16* __restrict__ Kbf,
    const u16* __restrict__ Vbf, float* __restrict__ Abase,
    u16* __restrict__ Obf) {
  int qb = blockIdx.x;
  int nh = blockIdx.y;
  int dir = blockIdx.z;
  int q0 = qb * 64;
  int k_start = dir == 0 ? q0 : (q0 >= 64 ? q0 - 64 : 0);
  int k_end = dir == 0 ? (q0 + 128 <= kW ? q0 + 128 : kW) : q0 + 64;
  int kfr = (k_end - k_start) >> 4;  // 4 or 8
  const u16* Q = Qbf + ((size_t)dir * 192 + nh) * kW * 64;
  const u16* K = Kbf + ((size_t)dir * 192 + nh) * kW * 64;
  const u16* V = Vbf + ((size_t)dir * 192 + nh) * 96 * kW;
  float* Aout = Abase + (size_t)dir * 50331648 + (size_t)nh * kW * kW;
  u16* Obase = Obf + (size_t)dir * 9437184;

  __shared__ __attribute__((aligned(16))) u16 smem[26880];
  u16* Qs = smem;           // [64][72]
  u16* Ks = smem + 4608;    // [128][72]
  u16* Ps = smem;           // [64][136] (aliases after barrier)
  u16* Vt = smem + 13824;   // [96][136]

  int tid = threadIdx.x;
  int wid = tid >> 6, lane = tid & 63;
  int lr = lane & 15, g = lane >> 4;

  for (int u = tid; u < 64 * 16; u += 256) {
    int row = u >> 4, c4 = (u & 15) * 4;
    *reinterpret_cast<us4*>(&Qs[row * 72 + c4]) =
        *reinterpret_cast<const us4*>(&Q[(size_t)(q0 + row) * 64 + c4]);
  }
  for (int u = tid; u < 128 * 16; u += 256) {
    int row = u >> 4, c4 = (u & 15) * 4;
    *reinterpret_cast<us4*>(&Ks[row * 72 + c4]) =
        *reinterpret_cast<const us4*>(&K[(size_t)(k_start + row) * 64 + c4]);
  }
  for (int u = tid; u < 96 * 32; u += 256) {
    int row = u >> 5, c4 = (u & 31) * 4;
    *reinterpret_cast<us4*>(&Vt[row * 136 + c4]) =
        *reinterpret_cast<const us4*>(&V[(size_t)row * kW + k_start + c4]);
  }
  __syncthreads();

  f32x4 sT[8];
#pragma unroll
  for (int kf = 0; kf < 8; ++kf) sT[kf] = f32x4{0.f, 0.f, 0.f, 0.f};
#pragma unroll
  for (int kc = 0; kc < 2; ++kc) {
    bf16x8 bq = *reinterpret_cast<const bf16x8*>(&Qs[(wid * 16 + lr) * 72 + kc * 32 + g * 8]);
#pragma unroll
    for (int kf = 0; kf < 8; ++kf) {
      bf16x8 ak = *reinterpret_cast<const bf16x8*>(&Ks[(kf * 16 + lr) * 72 + kc * 32 + g * 8]);
      sT[kf] = __builtin_amdgcn_mfma_f32_16x16x32_bf16(ak, bq, sT[kf], 0, 0, 0);
    }
  }

  int i = q0 + wid * 16 + lr;
  float mx = -INFINITY;
#pragma unroll
  for (int kf = 0; kf < 8; ++kf) {
#pragma unroll
    for (int r = 0; r < 4; ++r) {
      int jj = k_start + kf * 16 + g * 4 + r;
      bool valid = (jj < k_end) &&
                   (dir == 0 ? (jj >= i && jj - i <= 64) : (jj <= i && i - jj <= 64));
      float v = valid ? sT[kf][r] * 0.125f : -INFINITY;
      sT[kf][r] = v;
      mx = fmaxf(mx, v);
    }
  }
  mx = fmaxf(mx, __shfl_xor(mx, 16));
  mx = fmaxf(mx, __shfl_xor(mx, 32));
  float ssum = 0.f;
#pragma unroll
  for (int kf = 0; kf < 8; ++kf) {
#pragma unroll
    for (int r = 0; r < 4; ++r) {
      float e = __expf(sT[kf][r] - mx);
      sT[kf][r] = e;
      ssum += e;
    }
  }
  ssum += __shfl_xor(ssum, 16);
  ssum += __shfl_xor(ssum, 32);
  float inv = 1.f / ssum;

  __syncthreads();  // Qs/Ks reads done; smem becomes Ps

  {
    float* arow = Aout + (size_t)i * kW + k_start;
#pragma unroll
    for (int kf = 0; kf < 8; ++kf) {
      f32x4 pv;
      us4 pb;
#pragma unroll
      for (int r = 0; r < 4; ++r) {
        float p = sT[kf][r] * inv;
        p = (p > 0.01f) ? p : 0.f;
        pv[r] = p;
        pb[r] = f2bf(p);
      }
      *reinterpret_cast<us4*>(&Ps[(wid * 16 + lr) * 136 + kf * 16 + g * 4]) = pb;
      if (kf < kfr)
        __builtin_nontemporal_store(pv, reinterpret_cast<f32x4*>(arow + kf * 16 + g * 4));
    }
  }
  // zero-fill A outside the band
  {
    int row = tid >> 2, t4 = tid & 3;
    f32x4 z4 = {0.f, 0.f, 0.f, 0.f};
    float* arow = Aout + (size_t)(q0 + row) * kW;
    for (int c4 = t4; c4 < (k_start >> 2); c4 += 4)
      __builtin_nontemporal_store(z4, reinterpret_cast<f32x4*>(arow + c4 * 4));
    for (int c4 = (k_end >> 2) + t4; c4 < 128; c4 += 4)
      __builtin_nontemporal_store(z4, reinterpret_cast<f32x4*>(arow + c4 * 4));
  }
  __syncthreads();

  // PV
  f32x4 oacc[6];
#pragma unroll
  for (int ef = 0; ef < 6; ++ef) oacc[ef] = f32x4{0.f, 0.f, 0.f, 0.f};
#pragma unroll
  for (int kc = 0; kc < 4; ++kc) {
    bf16x8 ap = *reinterpret_cast<const bf16x8*>(&Ps[(wid * 16 + lr) * 136 + kc * 32 + g * 8]);
#pragma unroll
    for (int ef = 0; ef < 6; ++ef) {
      bf16x8 bv = *reinterpret_cast<const bf16x8*>(&Vt[(ef * 16 + lr) * 136 + kc * 32 + g * 8]);
      oacc[ef] = __builtin_amdgcn_mfma_f32_16x16x32_bf16(ap, bv, oacc[ef], 0, 0, 0);
    }
  }
  // transpose O through LDS for coalesced global write
  __syncthreads();
  u16* Os2 = smem;  // [64][104]
#pragma unroll
  for (int ef = 0; ef < 6; ++ef) {
    int e = ef * 16 + lr;
#pragma unroll
    for (int r = 0; r < 4; ++r)
      Os2[(wid * 16 + g * 4 + r) * 104 + e] = f2bf(oacc[ef][r]);
  }
  __syncthreads();
  int n_ = nh >> 1, h_ = nh & 1;
  for (int u = tid; u < 64 * 24; u += 256) {
    int q = u / 24, c4 = (u % 24) * 4;
    *reinterpret_cast<us4*>(&Obase[((size_t)n_ * kW + q0 + q) * kC + h_ * 96 + c4]) =
        *reinterpret_cast<const us4*>(&Os2[q * 104 + c4]);
  }
}

// ---------------- fused out-projection + FF + residuals + transpose-out ---------------
// B fragments direct from L2 (pre-converted bf16 weights).
__global__ void __launch_bounds__(256) projff_mfma(
    const u16* __restrict__ pfw,
    const float* __restrict__ bo0, const float* __restrict__ bo1,
    const float* __restrict__ fb0, const float* __restrict__ fb1,
    const u16* __restrict__ Obf, const u16* __restrict__ lraw,
    const u16* __restrict__ rraw, float* __restrict__ outbase) {
  int l0 = blockIdx.x * 64;
  int z = blockIdx.y;
  int dir = z / 96, n = z % 96;
  const u16* wo2 = pfw + (dir ? 36864 : 0);
  const u16* fw2 = pfw + 73728 + (dir ? 36864 : 0);
  const float* bo_ = dir ? bo1 : bo0;
  const float* fb_ = dir ? fb1 : fb0;
  const u16* Osrc = Obf + (size_t)dir * 9437184;
  const u16* resbf = dir ? rraw : lraw;
  float* outb = outbase + (size_t)dir * 9437184;
  int bb = n / kHH, h = n % kHH;

  __shared__ __attribute__((aligned(16))) u16 Xs[64 * 200];  // O tile, then lo_bf
  __shared__ __attribute__((aligned(16))) u16 Rs[64 * 200];  // residual tile

  int tid = threadIdx.x;
  int wid = tid >> 6, lane = tid & 63;
  int wm = wid >> 1, wn = wid & 1;
  int lr = lane & 15, g = lane >> 4;

  for (int u = tid; u < 64 * 48; u += 256) {
    int row = u / 48, q = u % 48;
    size_t src = ((size_t)n * kW + l0 + row) * kC + q * 4;
    *reinterpret_cast<us4*>(&Xs[row * 200 + q * 4]) =
        *reinterpret_cast<const us4*>(&Osrc[src]);
    *reinterpret_cast<us4*>(&Rs[row * 200 + q * 4]) =
        *reinterpret_cast<const us4*>(&resbf[src]);
  }
  __syncthreads();

  const u16* wobase = wo2 + (size_t)(wn * 96 + lr) * kC + g * 8;
  const u16* fwbase = fw2 + (size_t)(wn * 96 + lr) * kC + g * 8;

  // ---- proj phase ----
  f32x4 accp[2][6] = {};
#pragma unroll
  for (int c0 = 0; c0 < 192; c0 += 64) {
#pragma unroll
    for (int ks = 0; ks < 2; ++ks) {
      bf16x8 a[2], b[6];
#pragma unroll
      for (int m2 = 0; m2 < 2; ++m2)
        a[m2] = *reinterpret_cast<const bf16x8*>(
            &Xs[(wm * 32 + m2 * 16 + lr) * 200 + c0 + ks * 32 + g * 8]);
#pragma unroll
      for (int nf = 0; nf < 6; ++nf)
        b[nf] = *reinterpret_cast<const bf16x8*>(
            wobase + (size_t)nf * 16 * kC + c0 + ks * 32);
#pragma unroll
      for (int m2 = 0; m2 < 2; ++m2)
#pragma unroll
        for (int nf = 0; nf < 6; ++nf)
          accp[m2][nf] = __builtin_amdgcn_mfma_f32_16x16x32_bf16(a[m2], b[nf], accp[m2][nf], 0, 0, 0);
    }
  }
  // epilogue: lo = proj + bo + residual; fp32 kept in regs, bf16 into Xs
  __syncthreads();  // all proj reads of Xs done
#pragma unroll
  for (int nf = 0; nf < 6; ++nf) {
    int o = wn * 96 + nf * 16 + lr;
    float bv = bo_[o];
#pragma unroll
    for (int m2 = 0; m2 < 2; ++m2) {
#pragma unroll
      for (int r = 0; r < 4; ++r) {
        int l = wm * 32 + m2 * 16 + g * 4 + r;
        float v = accp[m2][nf][r] + bv + bf2f(Rs[l * 200 + o]);
        accp[m2][nf][r] = v;
        Xs[l * 200 + o] = f2bf(v);
      }
    }
  }
  __syncthreads();

  // ---- ff phase ----
  f32x4 accf[2][6] = {};
#pragma unroll
  for (int c0 = 0; c0 < 192; c0 += 64) {
#pragma unroll
    for (int ks = 0; ks < 2; ++ks) {
      bf16x8 a[2], b[6];
#pragma unroll
      for (int m2 = 0; m2 < 2; ++m2)
        a[m2] = *reinterpret_cast<const bf16x8*>(
            &Xs[(wm * 32 + m2 * 16 + lr) * 200 + c0 + ks * 32 + g * 8]);
#pragma unroll
      for (int nf = 0; nf < 6; ++nf)
        b[nf] = *reinterpret_cast<const bf16x8*>(
            fwbase + (size_t)nf * 16 * kC + c0 + ks * 32);
#pragma unroll
      for (int m2 = 0; m2 < 2; ++m2)
#pragma unroll
        for (int nf = 0; nf < 6; ++nf)
          accf[m2][nf] = __builtin_amdgcn_mfma_f32_16x16x32_bf16(a[m2], b[nf], accf[m2][nf], 0, 0, 0);
    }
  }
  // ff epilogue: out = ff + fb + lo (regs), float4 stores, [b,c,h,w] layout
#pragma unroll
  for (int nf = 0; nf < 6; ++nf) {
    int o = wn * 96 + nf * 16 + lr;
    float bv = fb_[o];
#pragma unroll
    for (int m2 = 0; m2 < 2; ++m2) {
      f32x4 ov;
#pragma unroll
      for (int r = 0; r < 4; ++r)
        ov[r] = accf[m2][nf][r] + bv + accp[m2][nf][r];
      int l = l0 + wm * 32 + m2 * 16 + g * 4;
      *reinterpret_cast<f32x4*>(&outb[(((size_t)bb * kC + o) * kHH + h) * kW + l]) = ov;
    }
  }
}

extern "C" void kernel_launch(void* const* d_in, const int* in_sizes, int n_in,
                              void* d_out, int out_size, void* d_ws, size_t ws_size,
                              hipStream_t stream) {
  const float* l = (const float*)d_in[0];
  const float* r = (const float*)d_in[1];
  float* out = (float*)d_out;
  float* ws = (float*)d_ws;

  u16* lnl_bf  = (u16*)(ws + 0);          // [96][512][192] bf16
  u16* lnr_bf  = (u16*)(ws + 4718592);
  u16* lraw_bf = (u16*)(ws + 9437184);
  u16* rraw_bf = (u16*)(ws + 14155776);
  u16* wall    = (u16*)(ws + 18874368);   // 516096 u16
  float* ball  = ws + 19136512;           // 896 f
  u16* Qbf     = (u16*)(ws + 19137536);   // [2][192][512][64] bf16
  u16* Kbf     = (u16*)(ws + 25428992);
  u16* Vbf     = (u16*)(ws + 31720448);   // [2][192][96][512] bf16
  u16* Obf     = (u16*)(ws + 41157632);   // [2][96][512][192] bf16
  u16* pfw     = (u16*)(ws + 50594816);   // 147456 u16: wo0,wo1,fw0,fw1

  ln_kernel<<<dim3(8, 96, 2), 256, 0, stream>>>(
      l, r, (const float*)d_in[2], (const float*)d_in[3],
      (const float*)d_in[4], (const float*)d_in[5],
      lnl_bf, lraw_bf, lnr_bf, rraw_bf);

  wprep_all<<<(516096 + 147456 + 896 + 255) / 256, 256, 0, stream>>>(
      (const float*)d_in[6], (const float*)d_in[8], (const float*)d_in[10],
      (const float*)d_in[14], (const float*)d_in[16], (const float*)d_in[18],
      (const float*)d_in[7], (const float*)d_in[9], (const float*)d_in[11],
      (const float*)d_in[15], (const float*)d_in[17], (const float*)d_in[19],
      (const float*)d_in[12], (const float*)d_in[20],
      (const float*)d_in[22], (const float*)d_in[24],
      wall, pfw, ball);

  conv_qk<<<dim3(4, 4, 96), 256, 0, stream>>>(lnl_bf, lnr_bf, wall, ball, Qbf, Kbf);
  conv_v<<<dim3(4, 2, 96), 256, 0, stream>>>(lraw_bf, rraw_bf, wall, ball, Vbf);

  attn_mfma<<<dim3(8, 192, 2), 256, 0, stream>>>(
      Qbf, Kbf, Vbf, out + (size_t)18874368, Obf);

  projff_mfma<<<dim3(8, 192), 256, 0, stream>>>(
      pfw, (const float*)d_in[13], (const float*)d_in[21],
      (const float*)d_in[23], (const float*)d_in[25],
      Obf, lraw_bf, rraw_bf, out);
}